// Round 1
// baseline (327.134 us; speedup 1.0000x reference)
//
#include <hip/hip_runtime.h>
#include <hip/hip_bf16.h>

#define NEG_SLOPE 0.2f
#define THR    256   // threads per block
#define NB     512   // fused grid blocks (must equal 2*THR for build-step reductions)
#define B1CAP  16    // per-block bucket cap, target edges
#define B2CAP  32    // per-block bucket cap, S edges
#define CAP1   512   // total edges into target (realistic ~21)
#define CAPS   64    // unique source nodes incl target (realistic ~21)
#define MAXDEG 256   // per-node in-degree cap in layer-1
#define NTAIL  (CAPS + 1)

// ws header: W[0]=c1 W[1]=ns W[4]=doneCnt W[5]=mean(bits)
#define OFF_PARTS  8
#define OFF_B1CNT  (OFF_PARTS + NB)
#define OFF_B1SRC  (OFF_B1CNT + NB)
#define OFF_B1EA   (OFF_B1SRC + NB * B1CAP)
#define OFF_B2CNT  (OFF_B1EA + NB * B1CAP)
#define OFF_B2SRC  (OFF_B2CNT + NB)
#define OFF_B2DST  (OFF_B2SRC + NB * B2CAP)
#define OFF_B2EA   (OFF_B2DST + NB * B2CAP)
#define OFF_L1SRC  (OFF_B2EA + NB * B2CAP)
#define OFF_L1EA   (OFF_L1SRC + CAP1)
#define OFF_SLIST  (OFF_L1EA + CAP1)
#define OFF_XL2    (OFF_SLIST + CAPS)
#define OFF_XR2    (OFF_XL2 + CAPS * 128)
#define OFF_FLAG1  (OFF_XR2 + 128)       // 2*NB words: [magic | ~magic]
#define OFF_FLAG2  (OFF_FLAG1 + 2 * NB)  // 2*NB words

#define MAG1 0x51C2A900u
#define MAG2 0x3E85C100u

__device__ __forceinline__ float us2f(unsigned short s) {
    union { unsigned int u; float f; } c;
    c.u = ((unsigned int)s) << 16;
    return c.f;
}
template<bool F32>
__device__ __forceinline__ float tld(const void* p, int i) {
    if (F32) return ((const float*)p)[i];
    return us2f(((const unsigned short*)p)[i]);
}
__device__ __forceinline__ float ald_f(const float* p) {
    return __hip_atomic_load(p, __ATOMIC_RELAXED, __HIP_MEMORY_SCOPE_AGENT);
}

// ---------------------------------------------------------------------------
// Poison-proof grid barrier: per-block dual magic flags. A uniform fill
// pattern (byte- or word-periodic poison) can never equal both m and ~m,
// so a freshly-poisoned workspace cannot fake a completed barrier. The
// finisher clears the flags, so even a replay WITHOUT re-poison is safe
// (every other ws word consumed across the barrier is rewritten each run).
__device__ __forceinline__ void flags_set(int* f, int bid, unsigned base) {
    unsigned m = base ^ (unsigned)bid;
    __hip_atomic_store((unsigned*)&f[bid],      m,  __ATOMIC_RELEASE, __HIP_MEMORY_SCOPE_AGENT);
    __hip_atomic_store((unsigned*)&f[NB + bid], ~m, __ATOMIC_RELEASE, __HIP_MEMORY_SCOPE_AGENT);
}
__device__ __forceinline__ void flags_wait(const int* f, int tid, unsigned base) {
    for (int i = tid; i < NB; i += THR) {
        unsigned m = base ^ (unsigned)i;
        while (__hip_atomic_load((const unsigned*)&f[i], __ATOMIC_ACQUIRE,
                                 __HIP_MEMORY_SCOPE_AGENT) != m)
            __builtin_amdgcn_s_sleep(2);
        while (__hip_atomic_load((const unsigned*)&f[NB + i], __ATOMIC_ACQUIRE,
                                 __HIP_MEMORY_SCOPE_AGENT) != ~m)
            __builtin_amdgcn_s_sleep(2);
    }
}

// ---------------------------------------------------------------------------
// Single fused kernel:
//   phase 1: all 512 blocks scan edges for dst==target + ea sum  -> b1 buckets
//   barrier 1 (dual-magic flags)
//   phase 2: all blocks build membership from b1 buckets, scan edges for
//            dst in S -> b2 buckets; block 0 additionally compacts l1 list,
//            computes mean, dedups slist (only needs phase-1 data)
//   barrier 2; blocks >= NTAIL exit
//   phase 3: blocks 0..ns-1 layer-1 per S-node; block CAPS finisher
// Co-residency: __launch_bounds__(THR,2) -> 2 blocks/CU x 256 CU = 512 = grid.
template<bool F32>
__device__ void fused_body(
    const void* __restrict__ x, const int* __restrict__ src,
    const int* __restrict__ dst, const void* __restrict__ ea,
    int tgt0, int E,
    const void* Wl1, const void* bl1, const void* Wr1, const void* br1,
    const void* We1, const void* att1, const void* b1,
    const void* Wl2, const void* bl2, const void* Wr2, const void* br2,
    const void* We2, const void* att2, const void* b2v,
    const void* Wfc, const void* bfc,
    void* __restrict__ out, int* __restrict__ W)
{
    const int tid = threadIdx.x, bid = blockIdx.x;
    const int gid = bid * THR + tid, gs = NB * THR;
    const int E4 = E >> 2, rem = E & 3;

    float* parts = (float*)(W + OFF_PARTS);
    int*   b1cnt = W + OFF_B1CNT;
    int*   b1src = W + OFF_B1SRC;
    float* b1ea  = (float*)(W + OFF_B1EA);
    int*   b2cnt = W + OFF_B2CNT;
    int*   b2src = W + OFF_B2SRC;
    int*   b2dst = W + OFF_B2DST;
    float* b2ea  = (float*)(W + OFF_B2EA);
    int*   l1src = W + OFF_L1SRC;
    float* l1ea  = (float*)(W + OFF_L1EA);
    int*   slist = W + OFF_SLIST;
    float* xl2   = (float*)(W + OFF_XL2);
    float* xr2   = (float*)(W + OFF_XR2);

    // ================= phase 1: scan1 =================
    {
        __shared__ float sRed1[4];
        __shared__ int   sCnt1;
        __shared__ int   sIb1[B1CAP];
        __shared__ float sFb1[B1CAP];
        if (tid == 0) sCnt1 = 0;
        __syncthreads();
        float sum = 0.f;
        for (int j = gid; j < E4; j += gs) {
            int4 d4 = ((const int4*)dst)[j];
            float v0, v1, v2, v3;
            if (F32) {
                float4 e4 = ((const float4*)ea)[j];
                v0 = e4.x; v1 = e4.y; v2 = e4.z; v3 = e4.w;
            } else {
                ushort4 u4 = ((const ushort4*)ea)[j];
                v0 = us2f(u4.x); v1 = us2f(u4.y); v2 = us2f(u4.z); v3 = us2f(u4.w);
            }
            sum += (v0 + v1) + (v2 + v3);
            int base = 4 * j;
            if (d4.x == tgt0) { int p = atomicAdd(&sCnt1, 1); if (p < B1CAP) { sIb1[p] = src[base+0]; sFb1[p] = v0; } }
            if (d4.y == tgt0) { int p = atomicAdd(&sCnt1, 1); if (p < B1CAP) { sIb1[p] = src[base+1]; sFb1[p] = v1; } }
            if (d4.z == tgt0) { int p = atomicAdd(&sCnt1, 1); if (p < B1CAP) { sIb1[p] = src[base+2]; sFb1[p] = v2; } }
            if (d4.w == tgt0) { int p = atomicAdd(&sCnt1, 1); if (p < B1CAP) { sIb1[p] = src[base+3]; sFb1[p] = v3; } }
        }
        if (gid < rem) {
            int i = E4 * 4 + gid;
            float v = tld<F32>(ea, i);
            sum += v;
            if (dst[i] == tgt0) { int p = atomicAdd(&sCnt1, 1); if (p < B1CAP) { sIb1[p] = src[i]; sFb1[p] = v; } }
        }
        for (int o = 32; o > 0; o >>= 1) sum += __shfl_down(sum, o);
        if ((tid & 63) == 0) sRed1[tid >> 6] = sum;
        __syncthreads();
        if (tid == 0) parts[bid] = sRed1[0] + sRed1[1] + sRed1[2] + sRed1[3];
        int bc = sCnt1 < B1CAP ? sCnt1 : B1CAP;
        if (tid == 0) b1cnt[bid] = bc;
        if (tid < bc) { b1src[bid * B1CAP + tid] = sIb1[tid]; b1ea[bid * B1CAP + tid] = sFb1[tid]; }
    }
    __syncthreads();
    __threadfence();
    if (tid == 0) flags_set(W + OFF_FLAG1, bid, MAG1);

    // ---- barrier 1: all b1 buckets + parts visible ----
    flags_wait(W + OFF_FLAG1, tid, MAG1);
    __syncthreads();
    __threadfence();

    // ================= phase 2: scan2 + build =================
    {
        __shared__ int   sS[CAPS];
        __shared__ int   sNs, sCnt2;
        __shared__ int   sIbs[B2CAP], sIbd[B2CAP];
        __shared__ float sFb2[B2CAP];
        __shared__ int   sPfx[THR];
        __shared__ float sRed2[4];

        if (tid == 0) { sS[0] = tgt0; sNs = 1; sCnt2 = 0; }
        __syncthreads();
        for (int bk = tid; bk < NB; bk += THR) {
            int c = b1cnt[bk]; if (c > B1CAP) c = B1CAP;
            for (int j = 0; j < c; j++) {
                int p = atomicAdd(&sNs, 1);
                if (p < CAPS) sS[p] = b1src[bk * B1CAP + j];
            }
        }
        __syncthreads();
        int ns = sNs < CAPS ? sNs : CAPS;

        #define CHECK(dv, idx)                                                 \
            do {                                                               \
                for (int j_ = 0; j_ < ns; j_++) {                              \
                    if (sS[j_] == (dv)) {                                      \
                        int p_ = atomicAdd(&sCnt2, 1);                         \
                        if (p_ < B2CAP) {                                      \
                            sIbs[p_] = src[idx]; sIbd[p_] = (dv);              \
                            sFb2[p_] = tld<F32>(ea, idx);                      \
                        }                                                      \
                        break;                                                 \
                    }                                                          \
                }                                                              \
            } while (0)
        for (int j = gid; j < E4; j += gs) {
            int4 d4 = ((const int4*)dst)[j];
            int base = 4 * j;
            CHECK(d4.x, base + 0);
            CHECK(d4.y, base + 1);
            CHECK(d4.z, base + 2);
            CHECK(d4.w, base + 3);
        }
        if (gid < rem) { int i = E4 * 4 + gid; CHECK(dst[i], i); }
        #undef CHECK
        __syncthreads();
        int bc = sCnt2 < B2CAP ? sCnt2 : B2CAP;
        if (tid == 0) b2cnt[bid] = bc;
        if (tid < bc) {
            b2src[bid * B2CAP + tid] = sIbs[tid];
            b2dst[bid * B2CAP + tid] = sIbd[tid];
            b2ea [bid * B2CAP + tid] = sFb2[tid];
        }

        // ---- build step (block 0 only; depends only on phase-1 data) ----
        if (bid == 0) {
            __syncthreads();
            int c0  = b1cnt[2*tid];    if (c0  > B1CAP) c0  = B1CAP;
            int c1b = b1cnt[2*tid+1];  if (c1b > B1CAP) c1b = B1CAP;
            int c = c0 + c1b;
            sPfx[tid] = c;
            __syncthreads();
            for (int o = 1; o < THR; o <<= 1) {
                int v = (tid >= o) ? sPfx[tid - o] : 0;
                __syncthreads();
                sPfx[tid] += v;
                __syncthreads();
            }
            int base = sPfx[tid] - c;
            int c1tot = sPfx[THR - 1];
            for (int j = 0; j < c0; j++) {
                int p = base + j;
                if (p < CAP1 - 1) { l1src[p] = b1src[2*tid*B1CAP + j]; l1ea[p] = b1ea[2*tid*B1CAP + j]; }
            }
            for (int j = 0; j < c1b; j++) {
                int p = base + c0 + j;
                if (p < CAP1 - 1) { l1src[p] = b1src[(2*tid+1)*B1CAP + j]; l1ea[p] = b1ea[(2*tid+1)*B1CAP + j]; }
            }
            float s = parts[tid] + parts[tid + THR];
            for (int o = 32; o > 0; o >>= 1) s += __shfl_down(s, o);
            if ((tid & 63) == 0) sRed2[tid >> 6] = s;
            __syncthreads();
            if (tid == 0) {
                float mean = (sRed2[0] + sRed2[1] + sRed2[2] + sRed2[3]) / (float)E;
                int c1 = c1tot < CAP1 - 1 ? c1tot : CAP1 - 1;
                l1src[c1] = tgt0; l1ea[c1] = mean;      // target self-loop
                c1++;
                int nsl = 0;                             // unique S (serial, ~21)
                for (int e = 0; e < c1; e++) {
                    int sv = l1src[e];
                    bool f = false;
                    for (int j = 0; j < nsl; j++) if (sS[j] == sv) { f = true; break; }
                    if (!f && nsl < CAPS) { sS[nsl] = sv; nsl++; }
                }
                for (int j = 0; j < nsl; j++) slist[j] = sS[j];
                W[0] = c1; W[1] = nsl; W[4] = 0;
                ((float*)W)[5] = mean;
            }
        }
    }
    __syncthreads();
    __threadfence();
    if (tid == 0) flags_set(W + OFF_FLAG2, bid, MAG2);

    if (bid >= NTAIL) return;   // scan-only blocks are done

    // ---- barrier 2: all b2 buckets + build outputs visible ----
    flags_wait(W + OFF_FLAG2, tid, MAG2);
    __syncthreads();
    __threadfence();

    // ================= phase 3: tail =================
    int ns = W[1]; if (ns > CAPS) ns = CAPS;
    int c1 = W[0]; if (c1 > CAP1) c1 = CAP1;
    float mean = ((float*)W)[5];

    if (bid < ns) {
        // ---------------- layer-1 for node s ----------------
        __shared__ float sWl[128], sBl[128], sWe[128], sAtt[128], sB1[128], sBase[128];
        __shared__ float sXs[MAXDEG], sEa2[MAXDEG], sL0[MAXDEG], sL1[MAXDEG], sH[128];
        __shared__ int sCnt3;
        int s = slist[bid];
        if (tid < 128) {
            sWl[tid] = tld<F32>(Wl1, tid);  sBl[tid] = tld<F32>(bl1, tid);
            sWe[tid] = tld<F32>(We1, tid);  sAtt[tid] = tld<F32>(att1, tid);
            sB1[tid] = tld<F32>(b1, tid);
            float xt = tld<F32>(x, s);
            sBase[tid] = xt * tld<F32>(Wr1, tid) + tld<F32>(br1, tid);
        }
        if (tid == 0) { sCnt3 = 1; sXs[0] = tld<F32>(x, s); sEa2[0] = mean; }  // self-loop
        __syncthreads();
        for (int bk = tid; bk < NB; bk += THR) {
            int c = b2cnt[bk]; if (c > B2CAP) c = B2CAP;
            for (int j = 0; j < c; j++) {
                if (b2dst[bk * B2CAP + j] == s) {
                    int p = atomicAdd(&sCnt3, 1);
                    if (p < MAXDEG) {
                        sXs[p] = tld<F32>(x, b2src[bk * B2CAP + j]);
                        sEa2[p] = b2ea[bk * B2CAP + j];
                    }
                }
            }
        }
        __syncthreads();
        int deg = sCnt3 < MAXDEG ? sCnt3 : MAXDEG;
        for (int i = tid; i < deg; i += THR) {
            float xs = sXs[i], eav = sEa2[i];
            float l0 = 0.f, l1v = 0.f;
            #pragma unroll 8
            for (int c2 = 0; c2 < 128; c2++) {
                float v = xs * sWl[c2] + sBl[c2] + sBase[c2] + eav * sWe[c2];
                v = v > 0.f ? v : NEG_SLOPE * v;
                float w = v * sAtt[c2];
                if (c2 < 64) l0 += w; else l1v += w;
            }
            sL0[i] = l0; sL1[i] = l1v;
        }
        __syncthreads();
        if (tid == 0) {
            float m0 = -1e30f, m1 = -1e30f;
            for (int i = 0; i < deg; i++) { m0 = fmaxf(m0, sL0[i]); m1 = fmaxf(m1, sL1[i]); }
            float s0 = 0.f, s1 = 0.f;
            for (int i = 0; i < deg; i++) {
                sL0[i] = __expf(sL0[i] - m0); s0 += sL0[i];
                sL1[i] = __expf(sL1[i] - m1); s1 += sL1[i];
            }
            float r0 = 1.f / s0, r1 = 1.f / s1;
            for (int i = 0; i < deg; i++) { sL0[i] *= r0; sL1[i] *= r1; }
        }
        __syncthreads();
        if (tid < 128) {
            bool hi = tid >= 64;
            float acc = 0.f;
            for (int i = 0; i < deg; i++) {
                float a = hi ? sL1[i] : sL0[i];
                acc += a * (sXs[i] * sWl[tid] + sBl[tid]);
            }
            acc += sB1[tid];
            sH[tid] = fmaxf(acc, 0.f);
        }
        __syncthreads();
        if (tid < 128) {
            float acc = tld<F32>(bl2, tid);
            #pragma unroll 16
            for (int k = 0; k < 128; k++) acc += sH[k] * tld<F32>(Wl2, k * 128 + tid);
            xl2[bid * 128 + tid] = acc;
            if (s == tgt0) {
                float a2 = tld<F32>(br2, tid);
                #pragma unroll 16
                for (int k = 0; k < 128; k++) a2 += sH[k] * tld<F32>(Wr2, k * 128 + tid);
                xr2[tid] = a2;
            }
        }
        __syncthreads();
        __threadfence();
        if (tid == 0)
            __hip_atomic_fetch_add(&W[4], 1, __ATOMIC_RELEASE, __HIP_MEMORY_SCOPE_AGENT);
    } else if (bid == CAPS) {
        // ---------------- finisher: layer-2 + FC ----------------
        __shared__ float sl0[CAP1], sl1[CAP1];
        __shared__ int sslot[CAP1];
        __shared__ float semb[128];
        __shared__ int sSf[CAPS];
        if (tid == 0) {
            while (__hip_atomic_load(&W[4], __ATOMIC_RELAXED, __HIP_MEMORY_SCOPE_AGENT) < ns)
                __builtin_amdgcn_s_sleep(8);
        }
        __syncthreads();
        __threadfence();
        if (tid < ns) sSf[tid] = slist[tid];
        __syncthreads();
        for (int e = tid; e < c1; e += THR) {
            int sv = l1src[e];
            int slot = 0;
            for (int j = 0; j < ns; j++) if (sSf[j] == sv) { slot = j; break; }
            sslot[e] = slot;
        }
        __syncthreads();
        float xr = 0.f, we = 0.f, at = 0.f;
        if (tid < 128) { xr = ald_f(&xr2[tid]); we = tld<F32>(We2, tid); at = tld<F32>(att2, tid); }
        for (int e = 0; e < c1; e++) {
            float w = 0.f;
            if (tid < 128) {
                float v = ald_f(&xl2[sslot[e] * 128 + tid]) + xr + l1ea[e] * we;
                v = v > 0.f ? v : NEG_SLOPE * v;
                w = v * at;
            }
            for (int o = 32; o > 0; o >>= 1) w += __shfl_down(w, o);
            if (tid == 0)  sl0[e] = w;
            if (tid == 64) sl1[e] = w;
        }
        __syncthreads();
        if (tid == 0) {
            float m0 = -1e30f, m1 = -1e30f;
            for (int e = 0; e < c1; e++) { m0 = fmaxf(m0, sl0[e]); m1 = fmaxf(m1, sl1[e]); }
            float s0 = 0.f, s1 = 0.f;
            for (int e = 0; e < c1; e++) {
                sl0[e] = __expf(sl0[e] - m0); s0 += sl0[e];
                sl1[e] = __expf(sl1[e] - m1); s1 += sl1[e];
            }
            float r0 = 1.f / s0, r1 = 1.f / s1;
            for (int e = 0; e < c1; e++) { sl0[e] *= r0; sl1[e] *= r1; }
        }
        __syncthreads();
        if (tid < 128) {
            bool hi = tid >= 64;
            float acc = tld<F32>(b2v, tid);
            for (int e = 0; e < c1; e++) {
                float a = hi ? sl1[e] : sl0[e];
                acc += a * ald_f(&xl2[sslot[e] * 128 + tid]);
            }
            semb[tid] = acc;
        }
        __syncthreads();
        if (tid < 128) {
            float o = tld<F32>(bfc, tid);
            #pragma unroll 16
            for (int c2 = 0; c2 < 128; c2++) o += semb[c2] * tld<F32>(Wfc, c2 * 128 + tid);
            if (F32) ((float*)out)[tid] = o;
            else     ((__hip_bfloat16*)out)[tid] = __float2bfloat16(o);
        }
        // clear barrier flags so a replay without re-poison stays correct
        __syncthreads();
        for (int i = tid; i < 4 * NB; i += THR) (W + OFF_FLAG1)[i] = 0;
    }
}

__global__ void __launch_bounds__(THR, 2)
k_fused(const void* __restrict__ x, const int* __restrict__ src,
        const int* __restrict__ dst, const void* __restrict__ ea,
        const int* __restrict__ tgt, int E,
        const void* Wl1, const void* bl1, const void* Wr1, const void* br1,
        const void* We1, const void* att1, const void* b1,
        const void* Wl2, const void* bl2, const void* Wr2, const void* br2,
        const void* We2, const void* att2, const void* b2v,
        const void* Wfc, const void* bfc,
        void* out, int* W)
{
    // dtype detect (per-block, identical result everywhere): bf16 halves of
    // f32 ~N(0,1) decode to tiny/huge exponents; real bf16 values don't.
    __shared__ int sWeird;
    if (threadIdx.x == 0) sWeird = 0;
    __syncthreads();
    {
        const unsigned short* u = (const unsigned short*)x;
        int c = 0;
        for (int i = threadIdx.x; i < 2048; i += THR) {
            int e2 = (u[i] >> 7) & 0xFF;
            if (e2 == 0 || e2 >= 0xC0) c++;
        }
        for (int o = 32; o > 0; o >>= 1) c += __shfl_down(c, o);
        if ((threadIdx.x & 63) == 0) atomicAdd(&sWeird, c);
    }
    __syncthreads();
    bool f32 = sWeird >= 64;
    int t = tgt[0];
    if (f32) fused_body<true >(x, src, dst, ea, t, E, Wl1, bl1, Wr1, br1, We1, att1, b1,
                               Wl2, bl2, Wr2, br2, We2, att2, b2v, Wfc, bfc, out, W);
    else     fused_body<false>(x, src, dst, ea, t, E, Wl1, bl1, Wr1, br1, We1, att1, b1,
                               Wl2, bl2, Wr2, br2, We2, att2, b2v, Wfc, bfc, out, W);
}

// ---------------------------------------------------------------------------
extern "C" void kernel_launch(void* const* d_in, const int* in_sizes, int n_in,
                              void* d_out, int out_size, void* d_ws, size_t ws_size,
                              hipStream_t stream) {
    const void* x    = d_in[0];
    const int*  eidx = (const int*)d_in[1];
    const void* eattr= d_in[2];
    const int*  tgt  = (const int*)d_in[3];
    const void* Wl1 = d_in[4],  *bl1 = d_in[5],  *Wr1 = d_in[6],  *br1 = d_in[7];
    const void* We1 = d_in[8],  *att1= d_in[9],  *b1  = d_in[10];
    const void* Wl2 = d_in[11], *bl2 = d_in[12], *Wr2 = d_in[13], *br2 = d_in[14];
    const void* We2 = d_in[15], *att2= d_in[16], *b2v = d_in[17];
    const void* Wfc = d_in[18], *bfc = d_in[19];

    int E = in_sizes[1] / 2;
    const int* src = eidx;
    const int* dst = eidx + E;
    int* W = (int*)d_ws;

    k_fused<<<NB, THR, 0, stream>>>(x, src, dst, eattr, tgt, E,
                                    Wl1, bl1, Wr1, br1, We1, att1, b1,
                                    Wl2, bl2, Wr2, br2, We2, att2, b2v,
                                    Wfc, bfc, d_out, W);
}

// Round 2
// 157.393 us; speedup vs baseline: 2.0784x; 2.0784x over previous
//
#include <hip/hip_runtime.h>
#include <hip/hip_bf16.h>

#define NEG_SLOPE 0.2f
#define THR    256   // threads per block
#define NB1    512   // scan1 blocks
#define NB2    512   // scan2 blocks
#define B1CAP  16    // per-block bucket cap, target edges (exp ~0.04/block)
#define B2CAP  32    // per-block bucket cap, S edges (exp ~1/block)
#define CAP1   512   // total edges into target (realistic ~21)
#define CAPS   64    // unique source nodes incl target (realistic ~21)
#define MAXDEG 256   // per-node in-degree cap in layer-1
#define NTAIL  (CAPS + 1)

// ws header: W[0]=c1 W[1]=ns W[3]=f32 W[4]=doneCnt W[5]=mean(bits)
#define OFF_PARTS  8
#define OFF_B1CNT  (OFF_PARTS + NB1)
#define OFF_B1SRC  (OFF_B1CNT + NB1)
#define OFF_B1EA   (OFF_B1SRC + NB1 * B1CAP)
#define OFF_B2CNT  (OFF_B1EA + NB1 * B1CAP)
#define OFF_B2SRC  (OFF_B2CNT + NB2)
#define OFF_B2DST  (OFF_B2SRC + NB2 * B2CAP)
#define OFF_B2EA   (OFF_B2DST + NB2 * B2CAP)
#define OFF_L1SRC  (OFF_B2EA + NB2 * B2CAP)
#define OFF_L1EA   (OFF_L1SRC + CAP1)
#define OFF_SLIST  (OFF_L1EA + CAP1)
#define OFF_XL2    (OFF_SLIST + CAPS)
#define OFF_XR2    (OFF_XL2 + CAPS * 128)

__device__ __forceinline__ float us2f(unsigned short s) {
    union { unsigned int u; float f; } c;
    c.u = ((unsigned int)s) << 16;
    return c.f;
}
template<bool F32>
__device__ __forceinline__ float tld(const void* p, int i) {
    if (F32) return ((const float*)p)[i];
    return us2f(((const unsigned short*)p)[i]);
}
__device__ __forceinline__ float ald_f(const float* p) {
    return __hip_atomic_load(p, __ATOMIC_RELAXED, __HIP_MEMORY_SCOPE_AGENT);
}

// ---------------------------------------------------------------------------
// K1: dtype detect (per-block) + bucketed scan for dst==target + ea partials.
// NOTE (R1 post-mortem): keep the 3-kernel structure. A fused single kernel
// with agent-scope acquire-poll grid barriers costs ~100 us PER BARRIER on
// gfx950 (cross-XCD coherence: every acquire poll invalidates caches at the
// fabric level; measured 240 us fused vs ~25 us for 3 kernels + graph gaps).
// Kernel boundaries ARE the cheap barrier on this chip.
template<bool F32>
__device__ void scan1_body(const int* __restrict__ src, const int* __restrict__ dst,
                           const void* __restrict__ ea, int t, int E,
                           int* __restrict__ W) {
    __shared__ float sRed[4];
    __shared__ int   sCnt;
    __shared__ int   sIb[B1CAP];
    __shared__ float sFb[B1CAP];
    const int tid = threadIdx.x, bid = blockIdx.x;
    const int gid = bid * THR + tid, gs = NB1 * THR;
    const int E4 = E >> 2, rem = E & 3;
    float* parts = (float*)(W + OFF_PARTS);
    int*   b1cnt = W + OFF_B1CNT;
    int*   b1src = W + OFF_B1SRC;
    float* b1ea  = (float*)(W + OFF_B1EA);

    if (tid == 0) sCnt = 0;
    __syncthreads();
    float sum = 0.f;
    for (int j = gid; j < E4; j += gs) {
        int4 d4 = ((const int4*)dst)[j];
        float v0, v1, v2, v3;
        if (F32) {
            float4 e4 = ((const float4*)ea)[j];
            v0 = e4.x; v1 = e4.y; v2 = e4.z; v3 = e4.w;
        } else {
            ushort4 u4 = ((const ushort4*)ea)[j];
            v0 = us2f(u4.x); v1 = us2f(u4.y); v2 = us2f(u4.z); v3 = us2f(u4.w);
        }
        sum += (v0 + v1) + (v2 + v3);
        int base = 4 * j;
        if (d4.x == t) { int p = atomicAdd(&sCnt, 1); if (p < B1CAP) { sIb[p] = src[base+0]; sFb[p] = v0; } }
        if (d4.y == t) { int p = atomicAdd(&sCnt, 1); if (p < B1CAP) { sIb[p] = src[base+1]; sFb[p] = v1; } }
        if (d4.z == t) { int p = atomicAdd(&sCnt, 1); if (p < B1CAP) { sIb[p] = src[base+2]; sFb[p] = v2; } }
        if (d4.w == t) { int p = atomicAdd(&sCnt, 1); if (p < B1CAP) { sIb[p] = src[base+3]; sFb[p] = v3; } }
    }
    if (gid < rem) {
        int i = E4 * 4 + gid;
        float v = tld<F32>(ea, i);
        sum += v;
        if (dst[i] == t) { int p = atomicAdd(&sCnt, 1); if (p < B1CAP) { sIb[p] = src[i]; sFb[p] = v; } }
    }
    for (int o = 32; o > 0; o >>= 1) sum += __shfl_down(sum, o);
    if ((tid & 63) == 0) sRed[tid >> 6] = sum;
    __syncthreads();
    if (tid == 0) parts[bid] = sRed[0] + sRed[1] + sRed[2] + sRed[3];
    int bc = sCnt < B1CAP ? sCnt : B1CAP;
    if (tid == 0) b1cnt[bid] = bc;
    if (tid < bc) { b1src[bid * B1CAP + tid] = sIb[tid]; b1ea[bid * B1CAP + tid] = sFb[tid]; }
}

__global__ void __launch_bounds__(THR)
k_scan1(const void* __restrict__ x, const int* __restrict__ src,
        const int* __restrict__ dst, const void* __restrict__ ea,
        const int* __restrict__ tgt, int E, int* __restrict__ W) {
    __shared__ int sWeird;
    if (threadIdx.x == 0) sWeird = 0;
    __syncthreads();
    {
        const unsigned short* u = (const unsigned short*)x;
        int c = 0;
        for (int i = threadIdx.x; i < 2048; i += THR) {
            int e2 = (u[i] >> 7) & 0xFF;
            if (e2 == 0 || e2 >= 0xC0) c++;
        }
        for (int o = 32; o > 0; o >>= 1) c += __shfl_down(c, o);
        if ((threadIdx.x & 63) == 0) atomicAdd(&sWeird, c);
    }
    __syncthreads();
    bool f32 = sWeird >= 64;
    if (blockIdx.x == 0 && threadIdx.x == 0) W[3] = f32 ? 1 : 0;
    int t = tgt[0];
    if (f32) scan1_body<true >(src, dst, ea, t, E, W);
    else     scan1_body<false>(src, dst, ea, t, E, W);
}

// ---------------------------------------------------------------------------
// K2: every block builds its own membership list straight from the b1 buckets
//     (duplicates harmless) -> NO cross-block waiting. Bucket-scan edges whose
//     dst is in S. Block 0 afterwards runs the build step (compact l1, mean,
//     dedup slist) for the next kernel.
template<bool F32>
__device__ void scan2_body(const int* __restrict__ src, const int* __restrict__ dst,
                           const void* __restrict__ ea, int tgt0, int E,
                           int* __restrict__ W) {
    __shared__ int   sS[CAPS];
    __shared__ int   sNs, sCnt;
    __shared__ int   sIb[B2CAP], sIb2[B2CAP];
    __shared__ float sFb[B2CAP];
    __shared__ int   sPfx[THR];
    __shared__ float sRed[4];
    const int tid = threadIdx.x, bid = blockIdx.x;
    const int gid = bid * THR + tid, gs = NB2 * THR;
    const int E4 = E >> 2, rem = E & 3;
    float* parts = (float*)(W + OFF_PARTS);
    int*   b1cnt = W + OFF_B1CNT;
    int*   b1src = W + OFF_B1SRC;
    float* b1ea  = (float*)(W + OFF_B1EA);
    int*   b2cnt = W + OFF_B2CNT;
    int*   b2src = W + OFF_B2SRC;
    int*   b2dst = W + OFF_B2DST;
    float* b2ea  = (float*)(W + OFF_B2EA);
    int*   l1src = W + OFF_L1SRC;
    float* l1ea  = (float*)(W + OFF_L1EA);
    int*   slist = W + OFF_SLIST;

    // ---- membership list from raw buckets (incl. target itself) ----
    if (tid == 0) { sS[0] = tgt0; sNs = 1; sCnt = 0; }
    __syncthreads();
    for (int bk = tid; bk < NB1; bk += THR) {
        int c = b1cnt[bk]; if (c > B1CAP) c = B1CAP;
        for (int j = 0; j < c; j++) {
            int p = atomicAdd(&sNs, 1);
            if (p < CAPS) sS[p] = b1src[bk * B1CAP + j];
        }
    }
    __syncthreads();
    int ns = sNs < CAPS ? sNs : CAPS;

    #define CHECK(dv, idx)                                                     \
        do {                                                                   \
            for (int j_ = 0; j_ < ns; j_++) {                                  \
                if (sS[j_] == (dv)) {                                          \
                    int p_ = atomicAdd(&sCnt, 1);                              \
                    if (p_ < B2CAP) {                                          \
                        sIb[p_] = src[idx]; sIb2[p_] = (dv);                   \
                        sFb[p_] = tld<F32>(ea, idx);                           \
                    }                                                          \
                    break;                                                     \
                }                                                              \
            }                                                                  \
        } while (0)
    for (int j = gid; j < E4; j += gs) {
        int4 d4 = ((const int4*)dst)[j];
        int base = 4 * j;
        CHECK(d4.x, base + 0);
        CHECK(d4.y, base + 1);
        CHECK(d4.z, base + 2);
        CHECK(d4.w, base + 3);
    }
    if (gid < rem) { int i = E4 * 4 + gid; CHECK(dst[i], i); }
    #undef CHECK
    __syncthreads();
    int bc = sCnt < B2CAP ? sCnt : B2CAP;
    if (tid == 0) b2cnt[bid] = bc;
    if (tid < bc) {
        b2src[bid * B2CAP + tid] = sIb[tid];
        b2dst[bid * B2CAP + tid] = sIb2[tid];
        b2ea [bid * B2CAP + tid] = sFb[tid];
    }

    // ---- build step (block 0 only; consumed by the NEXT kernel) ----
    if (bid == 0) {
        __syncthreads();
        int c0  = b1cnt[2*tid];    if (c0  > B1CAP) c0  = B1CAP;
        int c1b = b1cnt[2*tid+1];  if (c1b > B1CAP) c1b = B1CAP;
        int c = c0 + c1b;
        sPfx[tid] = c;
        __syncthreads();
        for (int o = 1; o < THR; o <<= 1) {
            int v = (tid >= o) ? sPfx[tid - o] : 0;
            __syncthreads();
            sPfx[tid] += v;
            __syncthreads();
        }
        int base = sPfx[tid] - c;
        int c1tot = sPfx[THR - 1];
        for (int j = 0; j < c0; j++) {
            int p = base + j;
            if (p < CAP1 - 1) { l1src[p] = b1src[2*tid*B1CAP + j]; l1ea[p] = b1ea[2*tid*B1CAP + j]; }
        }
        for (int j = 0; j < c1b; j++) {
            int p = base + c0 + j;
            if (p < CAP1 - 1) { l1src[p] = b1src[(2*tid+1)*B1CAP + j]; l1ea[p] = b1ea[(2*tid+1)*B1CAP + j]; }
        }
        float s = parts[tid] + parts[tid + THR];
        for (int o = 32; o > 0; o >>= 1) s += __shfl_down(s, o);
        if ((tid & 63) == 0) sRed[tid >> 6] = s;
        __syncthreads();
        if (tid == 0) {
            float mean = (sRed[0] + sRed[1] + sRed[2] + sRed[3]) / (float)E;
            int c1 = c1tot < CAP1 - 1 ? c1tot : CAP1 - 1;
            l1src[c1] = tgt0; l1ea[c1] = mean;      // target self-loop
            c1++;
            int nsl = 0;                             // unique S (serial, ~21)
            for (int e = 0; e < c1; e++) {
                int sv = l1src[e];
                bool f = false;
                for (int j = 0; j < nsl; j++) if (sS[j] == sv) { f = true; break; }
                if (!f && nsl < CAPS) { sS[nsl] = sv; nsl++; }
            }
            for (int j = 0; j < nsl; j++) slist[j] = sS[j];
            W[0] = c1; W[1] = nsl; W[4] = 0;
            ((float*)W)[5] = mean;
        }
    }
}

__global__ void __launch_bounds__(THR)
k_scan2(const int* __restrict__ src, const int* __restrict__ dst,
        const void* __restrict__ ea, const int* __restrict__ tgt,
        int E, int* __restrict__ W) {
    int t = tgt[0];
    if (W[3]) scan2_body<true >(src, dst, ea, t, E, W);
    else      scan2_body<false>(src, dst, ea, t, E, W);
}

// ---------------------------------------------------------------------------
// K3: blocks 0..ns-1 = layer-1 per S-node; block CAPS = finisher (layer-2+FC).
template<bool F32>
__device__ void tail_body(
    const void* __restrict__ x, int tgt0,
    const void* Wl1, const void* bl1, const void* Wr1, const void* br1,
    const void* We1, const void* att1, const void* b1,
    const void* Wl2, const void* bl2, const void* Wr2, const void* br2,
    const void* We2, const void* att2, const void* b2v,
    const void* Wfc, const void* bfc,
    void* __restrict__ out, int* __restrict__ W)
{
    const int tid = threadIdx.x, bid = blockIdx.x;
    int*   b2cnt = W + OFF_B2CNT;
    int*   b2src = W + OFF_B2SRC;
    int*   b2dst = W + OFF_B2DST;
    float* b2ea  = (float*)(W + OFF_B2EA);
    int*   l1src = W + OFF_L1SRC;
    float* l1ea  = (float*)(W + OFF_L1EA);
    int*   slist = W + OFF_SLIST;
    float* xl2   = (float*)(W + OFF_XL2);
    float* xr2   = (float*)(W + OFF_XR2);

    int ns = W[1]; if (ns > CAPS) ns = CAPS;
    int c1 = W[0]; if (c1 > CAP1) c1 = CAP1;
    float mean = ((float*)W)[5];

    if (bid < ns) {
        // ---------------- layer-1 for node s ----------------
        __shared__ float sWl[128], sBl[128], sWe[128], sAtt[128], sB1[128], sBase[128];
        __shared__ float sXs[MAXDEG], sEa2[MAXDEG], sL0[MAXDEG], sL1[MAXDEG], sH[128];
        __shared__ int sCnt;
        int s = slist[bid];
        if (tid < 128) {
            sWl[tid] = tld<F32>(Wl1, tid);  sBl[tid] = tld<F32>(bl1, tid);
            sWe[tid] = tld<F32>(We1, tid);  sAtt[tid] = tld<F32>(att1, tid);
            sB1[tid] = tld<F32>(b1, tid);
            float xt = tld<F32>(x, s);
            sBase[tid] = xt * tld<F32>(Wr1, tid) + tld<F32>(br1, tid);
        }
        if (tid == 0) { sCnt = 1; sXs[0] = tld<F32>(x, s); sEa2[0] = mean; }  // self-loop
        __syncthreads();
        for (int bk = tid; bk < NB2; bk += THR) {
            int c = b2cnt[bk]; if (c > B2CAP) c = B2CAP;
            for (int j = 0; j < c; j++) {
                if (b2dst[bk * B2CAP + j] == s) {
                    int p = atomicAdd(&sCnt, 1);
                    if (p < MAXDEG) {
                        sXs[p] = tld<F32>(x, b2src[bk * B2CAP + j]);
                        sEa2[p] = b2ea[bk * B2CAP + j];
                    }
                }
            }
        }
        __syncthreads();
        int deg = sCnt < MAXDEG ? sCnt : MAXDEG;
        for (int i = tid; i < deg; i += THR) {
            float xs = sXs[i], eav = sEa2[i];
            float l0 = 0.f, l1v = 0.f;
            #pragma unroll 8
            for (int c2 = 0; c2 < 128; c2++) {
                float v = xs * sWl[c2] + sBl[c2] + sBase[c2] + eav * sWe[c2];
                v = v > 0.f ? v : NEG_SLOPE * v;
                float w = v * sAtt[c2];
                if (c2 < 64) l0 += w; else l1v += w;
            }
            sL0[i] = l0; sL1[i] = l1v;
        }
        __syncthreads();
        if (tid == 0) {
            float m0 = -1e30f, m1 = -1e30f;
            for (int i = 0; i < deg; i++) { m0 = fmaxf(m0, sL0[i]); m1 = fmaxf(m1, sL1[i]); }
            float s0 = 0.f, s1 = 0.f;
            for (int i = 0; i < deg; i++) {
                sL0[i] = __expf(sL0[i] - m0); s0 += sL0[i];
                sL1[i] = __expf(sL1[i] - m1); s1 += sL1[i];
            }
            float r0 = 1.f / s0, r1 = 1.f / s1;
            for (int i = 0; i < deg; i++) { sL0[i] *= r0; sL1[i] *= r1; }
        }
        __syncthreads();
        if (tid < 128) {
            bool hi = tid >= 64;
            float acc = 0.f;
            for (int i = 0; i < deg; i++) {
                float a = hi ? sL1[i] : sL0[i];
                acc += a * (sXs[i] * sWl[tid] + sBl[tid]);
            }
            acc += sB1[tid];
            sH[tid] = fmaxf(acc, 0.f);
        }
        __syncthreads();
        if (tid < 128) {
            float acc = tld<F32>(bl2, tid);
            #pragma unroll 16
            for (int k = 0; k < 128; k++) acc += sH[k] * tld<F32>(Wl2, k * 128 + tid);
            xl2[bid * 128 + tid] = acc;
            if (s == tgt0) {
                float a2 = tld<F32>(br2, tid);
                #pragma unroll 16
                for (int k = 0; k < 128; k++) a2 += sH[k] * tld<F32>(Wr2, k * 128 + tid);
                xr2[tid] = a2;
            }
        }
        __syncthreads();
        __threadfence();
        if (tid == 0)
            __hip_atomic_fetch_add(&W[4], 1, __ATOMIC_RELEASE, __HIP_MEMORY_SCOPE_AGENT);
    } else if (bid == CAPS) {
        // ---------------- finisher: layer-2 + FC ----------------
        __shared__ float sl0[CAP1], sl1[CAP1];
        __shared__ int sslot[CAP1];
        __shared__ float semb[128];
        __shared__ int sS[CAPS];
        if (tid == 0) {
            // single-thread relaxed poll with backoff (narrow spin: 1 probe line)
            while (__hip_atomic_load(&W[4], __ATOMIC_RELAXED, __HIP_MEMORY_SCOPE_AGENT) < ns)
                __builtin_amdgcn_s_sleep(32);
        }
        __syncthreads();
        __threadfence();
        if (tid < ns) sS[tid] = slist[tid];
        __syncthreads();
        for (int e = tid; e < c1; e += THR) {
            int sv = l1src[e];
            int slot = 0;
            for (int j = 0; j < ns; j++) if (sS[j] == sv) { slot = j; break; }
            sslot[e] = slot;
        }
        __syncthreads();
        float xr = 0.f, we = 0.f, at = 0.f;
        if (tid < 128) { xr = ald_f(&xr2[tid]); we = tld<F32>(We2, tid); at = tld<F32>(att2, tid); }
        for (int e = 0; e < c1; e++) {
            float w = 0.f;
            if (tid < 128) {
                float v = ald_f(&xl2[sslot[e] * 128 + tid]) + xr + l1ea[e] * we;
                v = v > 0.f ? v : NEG_SLOPE * v;
                w = v * at;
            }
            for (int o = 32; o > 0; o >>= 1) w += __shfl_down(w, o);
            if (tid == 0)  sl0[e] = w;
            if (tid == 64) sl1[e] = w;
        }
        __syncthreads();
        if (tid == 0) {
            float m0 = -1e30f, m1 = -1e30f;
            for (int e = 0; e < c1; e++) { m0 = fmaxf(m0, sl0[e]); m1 = fmaxf(m1, sl1[e]); }
            float s0 = 0.f, s1 = 0.f;
            for (int e = 0; e < c1; e++) {
                sl0[e] = __expf(sl0[e] - m0); s0 += sl0[e];
                sl1[e] = __expf(sl1[e] - m1); s1 += sl1[e];
            }
            float r0 = 1.f / s0, r1 = 1.f / s1;
            for (int e = 0; e < c1; e++) { sl0[e] *= r0; sl1[e] *= r1; }
        }
        __syncthreads();
        if (tid < 128) {
            bool hi = tid >= 64;
            float acc = tld<F32>(b2v, tid);
            for (int e = 0; e < c1; e++) {
                float a = hi ? sl1[e] : sl0[e];
                acc += a * ald_f(&xl2[sslot[e] * 128 + tid]);
            }
            semb[tid] = acc;
        }
        __syncthreads();
        if (tid < 128) {
            float o = tld<F32>(bfc, tid);
            #pragma unroll 16
            for (int c2 = 0; c2 < 128; c2++) o += semb[c2] * tld<F32>(Wfc, c2 * 128 + tid);
            if (F32) ((float*)out)[tid] = o;
            else     ((__hip_bfloat16*)out)[tid] = __float2bfloat16(o);
        }
    }
}

__global__ void __launch_bounds__(THR)
k_tail(const void* x, const int* tgt,
       const void* Wl1, const void* bl1, const void* Wr1, const void* br1,
       const void* We1, const void* att1, const void* b1,
       const void* Wl2, const void* bl2, const void* Wr2, const void* br2,
       const void* We2, const void* att2, const void* b2v,
       const void* Wfc, const void* bfc,
       void* out, int* W)
{
    int t = tgt[0];
    if (W[3]) tail_body<true >(x, t, Wl1, bl1, Wr1, br1, We1, att1, b1,
                               Wl2, bl2, Wr2, br2, We2, att2, b2v, Wfc, bfc, out, W);
    else      tail_body<false>(x, t, Wl1, bl1, Wr1, br1, We1, att1, b1,
                               Wl2, bl2, Wr2, br2, We2, att2, b2v, Wfc, bfc, out, W);
}

// ---------------------------------------------------------------------------
extern "C" void kernel_launch(void* const* d_in, const int* in_sizes, int n_in,
                              void* d_out, int out_size, void* d_ws, size_t ws_size,
                              hipStream_t stream) {
    const void* x    = d_in[0];
    const int*  eidx = (const int*)d_in[1];
    const void* eattr= d_in[2];
    const int*  tgt  = (const int*)d_in[3];
    const void* Wl1 = d_in[4],  *bl1 = d_in[5],  *Wr1 = d_in[6],  *br1 = d_in[7];
    const void* We1 = d_in[8],  *att1= d_in[9],  *b1  = d_in[10];
    const void* Wl2 = d_in[11], *bl2 = d_in[12], *Wr2 = d_in[13], *br2 = d_in[14];
    const void* We2 = d_in[15], *att2= d_in[16], *b2v = d_in[17];
    const void* Wfc = d_in[18], *bfc = d_in[19];

    int E = in_sizes[1] / 2;
    const int* src = eidx;
    const int* dst = eidx + E;
    int* W = (int*)d_ws;

    k_scan1<<<NB1, THR, 0, stream>>>(x, src, dst, eattr, tgt, E, W);
    k_scan2<<<NB2, THR, 0, stream>>>(src, dst, eattr, tgt, E, W);
    k_tail <<<NTAIL, THR, 0, stream>>>(x, tgt, Wl1, bl1, Wr1, br1, We1, att1, b1,
                                       Wl2, bl2, Wr2, br2, We2, att2, b2v,
                                       Wfc, bfc, d_out, W);
}

// Round 3
// 147.145 us; speedup vs baseline: 2.2232x; 1.0696x over previous
//
#include <hip/hip_runtime.h>
#include <hip/hip_bf16.h>

#define NEG_SLOPE 0.2f
#define THR    256   // threads per block
#define NB1    512   // scan1 blocks
#define NB2    512   // scan2 blocks
#define B1CAP  16    // per-block bucket cap, target edges (exp ~0.04/block)
#define B2CAP  32    // per-block bucket cap, S edges (exp ~1/block)
#define CAP1   512   // total edges into target (realistic ~21)
#define CAPS   64    // unique source nodes incl target (realistic ~21)
#define MAXDEG 256   // per-node in-degree cap in layer-1
#define NTAIL  (CAPS + 1)

// ws header: W[0]=c1 W[1]=ns W[3]=f32 W[4]=doneCnt W[5]=mean(bits)
#define OFF_PARTS  8
#define OFF_B1CNT  (OFF_PARTS + NB1)
#define OFF_B1SRC  (OFF_B1CNT + NB1)
#define OFF_B1EA   (OFF_B1SRC + NB1 * B1CAP)
#define OFF_B2CNT  (OFF_B1EA + NB1 * B1CAP)
#define OFF_B2SRC  (OFF_B2CNT + NB2)
#define OFF_B2DST  (OFF_B2SRC + NB2 * B2CAP)
#define OFF_B2EA   (OFF_B2DST + NB2 * B2CAP)
#define OFF_L1SRC  (OFF_B2EA + NB2 * B2CAP)
#define OFF_L1EA   (OFF_L1SRC + CAP1)
#define OFF_SLIST  (OFF_L1EA + CAP1)
#define OFF_XL2    (OFF_SLIST + CAPS)
#define OFF_XR2    (OFF_XL2 + CAPS * 128)

__device__ __forceinline__ float us2f(unsigned short s) {
    union { unsigned int u; float f; } c;
    c.u = ((unsigned int)s) << 16;
    return c.f;
}
template<bool F32>
__device__ __forceinline__ float tld(const void* p, int i) {
    if (F32) return ((const float*)p)[i];
    return us2f(((const unsigned short*)p)[i]);
}
__device__ __forceinline__ float ald_f(const float* p) {
    return __hip_atomic_load(p, __ATOMIC_RELAXED, __HIP_MEMORY_SCOPE_AGENT);
}

// ---------------------------------------------------------------------------
// K1: dtype detect (per-block) + bucketed scan for dst==target + ea partials.
// NOTE (R1 post-mortem): keep the 3-kernel structure. A fused single kernel
// with agent-scope acquire-poll grid barriers costs ~100 us PER BARRIER on
// gfx950 (cross-XCD coherence invalidation storm; measured 240 us fused vs
// ~25 us for 3 kernels + graph gaps). Kernel boundaries ARE the cheap barrier.
template<bool F32>
__device__ void scan1_body(const int* __restrict__ src, const int* __restrict__ dst,
                           const void* __restrict__ ea, int t, int E,
                           int* __restrict__ W) {
    __shared__ float sRed[4];
    __shared__ int   sCnt;
    __shared__ int   sIb[B1CAP];
    __shared__ float sFb[B1CAP];
    const int tid = threadIdx.x, bid = blockIdx.x;
    const int gid = bid * THR + tid, gs = NB1 * THR;
    const int E4 = E >> 2, rem = E & 3;
    float* parts = (float*)(W + OFF_PARTS);
    int*   b1cnt = W + OFF_B1CNT;
    int*   b1src = W + OFF_B1SRC;
    float* b1ea  = (float*)(W + OFF_B1EA);

    if (tid == 0) sCnt = 0;
    __syncthreads();
    float sum = 0.f;
    for (int j = gid; j < E4; j += gs) {
        int4 d4 = ((const int4*)dst)[j];
        float v0, v1, v2, v3;
        if (F32) {
            float4 e4 = ((const float4*)ea)[j];
            v0 = e4.x; v1 = e4.y; v2 = e4.z; v3 = e4.w;
        } else {
            ushort4 u4 = ((const ushort4*)ea)[j];
            v0 = us2f(u4.x); v1 = us2f(u4.y); v2 = us2f(u4.z); v3 = us2f(u4.w);
        }
        sum += (v0 + v1) + (v2 + v3);
        int base = 4 * j;
        if (d4.x == t) { int p = atomicAdd(&sCnt, 1); if (p < B1CAP) { sIb[p] = src[base+0]; sFb[p] = v0; } }
        if (d4.y == t) { int p = atomicAdd(&sCnt, 1); if (p < B1CAP) { sIb[p] = src[base+1]; sFb[p] = v1; } }
        if (d4.z == t) { int p = atomicAdd(&sCnt, 1); if (p < B1CAP) { sIb[p] = src[base+2]; sFb[p] = v2; } }
        if (d4.w == t) { int p = atomicAdd(&sCnt, 1); if (p < B1CAP) { sIb[p] = src[base+3]; sFb[p] = v3; } }
    }
    if (gid < rem) {
        int i = E4 * 4 + gid;
        float v = tld<F32>(ea, i);
        sum += v;
        if (dst[i] == t) { int p = atomicAdd(&sCnt, 1); if (p < B1CAP) { sIb[p] = src[i]; sFb[p] = v; } }
    }
    for (int o = 32; o > 0; o >>= 1) sum += __shfl_down(sum, o);
    if ((tid & 63) == 0) sRed[tid >> 6] = sum;
    __syncthreads();
    if (tid == 0) parts[bid] = sRed[0] + sRed[1] + sRed[2] + sRed[3];
    int bc = sCnt < B1CAP ? sCnt : B1CAP;
    if (tid == 0) b1cnt[bid] = bc;
    if (tid < bc) { b1src[bid * B1CAP + tid] = sIb[tid]; b1ea[bid * B1CAP + tid] = sFb[tid]; }
}

__global__ void __launch_bounds__(THR)
k_scan1(const void* __restrict__ x, const int* __restrict__ src,
        const int* __restrict__ dst, const void* __restrict__ ea,
        const int* __restrict__ tgt, int E, int* __restrict__ W) {
    __shared__ int sWeird;
    if (threadIdx.x == 0) sWeird = 0;
    __syncthreads();
    {
        const unsigned short* u = (const unsigned short*)x;
        int c = 0;
        for (int i = threadIdx.x; i < 2048; i += THR) {
            int e2 = (u[i] >> 7) & 0xFF;
            if (e2 == 0 || e2 >= 0xC0) c++;
        }
        for (int o = 32; o > 0; o >>= 1) c += __shfl_down(c, o);
        if ((threadIdx.x & 63) == 0) atomicAdd(&sWeird, c);
    }
    __syncthreads();
    bool f32 = sWeird >= 64;
    if (blockIdx.x == 0 && threadIdx.x == 0) W[3] = f32 ? 1 : 0;
    int t = tgt[0];
    if (f32) scan1_body<true >(src, dst, ea, t, E, W);
    else     scan1_body<false>(src, dst, ea, t, E, W);
}

// ---------------------------------------------------------------------------
// K2: every block builds its own membership list straight from the b1 buckets
//     (duplicates harmless) -> NO cross-block waiting. Bucket-scan edges whose
//     dst is in S. Block 0 afterwards runs the build step (compact l1, mean,
//     dedup slist) for the next kernel.
template<bool F32>
__device__ void scan2_body(const int* __restrict__ src, const int* __restrict__ dst,
                           const void* __restrict__ ea, int tgt0, int E,
                           int* __restrict__ W) {
    __shared__ int   sS[CAPS];
    __shared__ int   sNs, sCnt;
    __shared__ int   sIb[B2CAP], sIb2[B2CAP];
    __shared__ float sFb[B2CAP];
    __shared__ int   sPfx[THR];
    __shared__ float sRed[4];
    const int tid = threadIdx.x, bid = blockIdx.x;
    const int gid = bid * THR + tid, gs = NB2 * THR;
    const int E4 = E >> 2, rem = E & 3;
    float* parts = (float*)(W + OFF_PARTS);
    int*   b1cnt = W + OFF_B1CNT;
    int*   b1src = W + OFF_B1SRC;
    float* b1ea  = (float*)(W + OFF_B1EA);
    int*   b2cnt = W + OFF_B2CNT;
    int*   b2src = W + OFF_B2SRC;
    int*   b2dst = W + OFF_B2DST;
    float* b2ea  = (float*)(W + OFF_B2EA);
    int*   l1src = W + OFF_L1SRC;
    float* l1ea  = (float*)(W + OFF_L1EA);
    int*   slist = W + OFF_SLIST;

    // ---- membership list from raw buckets (incl. target itself) ----
    if (tid == 0) { sS[0] = tgt0; sNs = 1; sCnt = 0; }
    __syncthreads();
    for (int bk = tid; bk < NB1; bk += THR) {
        int c = b1cnt[bk]; if (c > B1CAP) c = B1CAP;
        for (int j = 0; j < c; j++) {
            int p = atomicAdd(&sNs, 1);
            if (p < CAPS) sS[p] = b1src[bk * B1CAP + j];
        }
    }
    __syncthreads();
    int ns = sNs < CAPS ? sNs : CAPS;

    #define CHECK(dv, idx)                                                     \
        do {                                                                   \
            for (int j_ = 0; j_ < ns; j_++) {                                  \
                if (sS[j_] == (dv)) {                                          \
                    int p_ = atomicAdd(&sCnt, 1);                              \
                    if (p_ < B2CAP) {                                          \
                        sIb[p_] = src[idx]; sIb2[p_] = (dv);                   \
                        sFb[p_] = tld<F32>(ea, idx);                           \
                    }                                                          \
                    break;                                                     \
                }                                                              \
            }                                                                  \
        } while (0)
    for (int j = gid; j < E4; j += gs) {
        int4 d4 = ((const int4*)dst)[j];
        int base = 4 * j;
        CHECK(d4.x, base + 0);
        CHECK(d4.y, base + 1);
        CHECK(d4.z, base + 2);
        CHECK(d4.w, base + 3);
    }
    if (gid < rem) { int i = E4 * 4 + gid; CHECK(dst[i], i); }
    #undef CHECK
    __syncthreads();
    int bc = sCnt < B2CAP ? sCnt : B2CAP;
    if (tid == 0) b2cnt[bid] = bc;
    if (tid < bc) {
        b2src[bid * B2CAP + tid] = sIb[tid];
        b2dst[bid * B2CAP + tid] = sIb2[tid];
        b2ea [bid * B2CAP + tid] = sFb[tid];
    }

    // ---- build step (block 0 only; consumed by the NEXT kernel) ----
    if (bid == 0) {
        __syncthreads();
        int c0  = b1cnt[2*tid];    if (c0  > B1CAP) c0  = B1CAP;
        int c1b = b1cnt[2*tid+1];  if (c1b > B1CAP) c1b = B1CAP;
        int c = c0 + c1b;
        sPfx[tid] = c;
        __syncthreads();
        for (int o = 1; o < THR; o <<= 1) {
            int v = (tid >= o) ? sPfx[tid - o] : 0;
            __syncthreads();
            sPfx[tid] += v;
            __syncthreads();
        }
        int base = sPfx[tid] - c;
        int c1tot = sPfx[THR - 1];
        for (int j = 0; j < c0; j++) {
            int p = base + j;
            if (p < CAP1 - 1) { l1src[p] = b1src[2*tid*B1CAP + j]; l1ea[p] = b1ea[2*tid*B1CAP + j]; }
        }
        for (int j = 0; j < c1b; j++) {
            int p = base + c0 + j;
            if (p < CAP1 - 1) { l1src[p] = b1src[(2*tid+1)*B1CAP + j]; l1ea[p] = b1ea[(2*tid+1)*B1CAP + j]; }
        }
        float s = parts[tid] + parts[tid + THR];
        for (int o = 32; o > 0; o >>= 1) s += __shfl_down(s, o);
        if ((tid & 63) == 0) sRed[tid >> 6] = s;
        __syncthreads();
        if (tid == 0) {
            float mean = (sRed[0] + sRed[1] + sRed[2] + sRed[3]) / (float)E;
            int c1 = c1tot < CAP1 - 1 ? c1tot : CAP1 - 1;
            l1src[c1] = tgt0; l1ea[c1] = mean;      // target self-loop
            c1++;
            int nsl = 0;                             // unique S (serial, ~21)
            for (int e = 0; e < c1; e++) {
                int sv = l1src[e];
                bool f = false;
                for (int j = 0; j < nsl; j++) if (sS[j] == sv) { f = true; break; }
                if (!f && nsl < CAPS) { sS[nsl] = sv; nsl++; }
            }
            for (int j = 0; j < nsl; j++) slist[j] = sS[j];
            W[0] = c1; W[1] = nsl; W[4] = 0;
            ((float*)W)[5] = mean;
        }
    }
}

__global__ void __launch_bounds__(THR)
k_scan2(const int* __restrict__ src, const int* __restrict__ dst,
        const void* __restrict__ ea, const int* __restrict__ tgt,
        int E, int* __restrict__ W) {
    int t = tgt[0];
    if (W[3]) scan2_body<true >(src, dst, ea, t, E, W);
    else      scan2_body<false>(src, dst, ea, t, E, W);
}

// ---------------------------------------------------------------------------
// K3: blocks 0..ns-1 = layer-1 per S-node; block CAPS = finisher (layer-2+FC).
// R2 post-mortem: k_tail was 45 us, pure latency chains (VALUBusy 0.1%).
// Fixes: (a) finisher hoists all spin-independent work BEFORE the spin and
// L2-warms Wfc; (b) post-spin xl2/xr2 are bulk-loaded into LDS in one parallel
// burst (independent relaxed-atomic loads pipeline) instead of ~50 serialized
// agent-scope round-trips; (c) wave-parallel softmax; (d) split-k GEMVs.
template<bool F32>
__device__ void tail_body(
    const void* __restrict__ x, int tgt0,
    const void* Wl1, const void* bl1, const void* Wr1, const void* br1,
    const void* We1, const void* att1, const void* b1,
    const void* Wl2, const void* bl2, const void* Wr2, const void* br2,
    const void* We2, const void* att2, const void* b2v,
    const void* Wfc, const void* bfc,
    void* __restrict__ out, int* __restrict__ W)
{
    const int tid = threadIdx.x, bid = blockIdx.x;
    int*   b2cnt = W + OFF_B2CNT;
    int*   b2src = W + OFF_B2SRC;
    int*   b2dst = W + OFF_B2DST;
    float* b2ea  = (float*)(W + OFF_B2EA);
    int*   l1src = W + OFF_L1SRC;
    float* l1ea  = (float*)(W + OFF_L1EA);
    int*   slist = W + OFF_SLIST;
    float* xl2   = (float*)(W + OFF_XL2);
    float* xr2   = (float*)(W + OFF_XR2);

    int ns = W[1]; if (ns > CAPS) ns = CAPS;
    int c1 = W[0]; if (c1 > CAP1) c1 = CAP1;
    float mean = ((float*)W)[5];

    if (bid < ns) {
        // ---------------- layer-1 for node s ----------------
        __shared__ float sWl[128], sBl[128], sWe[128], sAtt[128], sB1[128], sBase[128];
        __shared__ float sXs[MAXDEG], sEa2[MAXDEG], sL0[MAXDEG], sL1[MAXDEG], sH[128];
        __shared__ float sPartL[THR];
        __shared__ int sCnt;
        int s = slist[bid];
        if (tid < 128) {
            sWl[tid] = tld<F32>(Wl1, tid);  sBl[tid] = tld<F32>(bl1, tid);
            sWe[tid] = tld<F32>(We1, tid);  sAtt[tid] = tld<F32>(att1, tid);
            sB1[tid] = tld<F32>(b1, tid);
            float xt = tld<F32>(x, s);
            sBase[tid] = xt * tld<F32>(Wr1, tid) + tld<F32>(br1, tid);
        }
        if (tid == 0) { sCnt = 1; sXs[0] = tld<F32>(x, s); sEa2[0] = mean; }  // self-loop
        __syncthreads();
        for (int bk = tid; bk < NB2; bk += THR) {
            int c = b2cnt[bk]; if (c > B2CAP) c = B2CAP;
            for (int j = 0; j < c; j++) {
                if (b2dst[bk * B2CAP + j] == s) {
                    int p = atomicAdd(&sCnt, 1);
                    if (p < MAXDEG) {
                        sXs[p] = tld<F32>(x, b2src[bk * B2CAP + j]);
                        sEa2[p] = b2ea[bk * B2CAP + j];
                    }
                }
            }
        }
        __syncthreads();
        int deg = sCnt < MAXDEG ? sCnt : MAXDEG;
        // logits: 2 threads per edge (one per head), 64 channels each
        {
            int i0 = tid >> 1, half = tid & 1, c0 = half << 6;
            for (int i = i0; i < deg; i += 128) {
                float xs = sXs[i], eav = sEa2[i];
                float acc = 0.f;
                #pragma unroll 8
                for (int c2 = 0; c2 < 64; c2++) {
                    int c = c0 + c2;
                    float v = xs * sWl[c] + sBl[c] + sBase[c] + eav * sWe[c];
                    v = v > 0.f ? v : NEG_SLOPE * v;
                    acc += v * sAtt[c];
                }
                if (half == 0) sL0[i] = acc; else sL1[i] = acc;
            }
        }
        __syncthreads();
        // wave-parallel softmax: wave0 = head0, wave1 = head1
        {
            int lane = tid & 63, wv = tid >> 6;
            if (wv < 2) {
                float* sl = wv ? sL1 : sL0;
                float m = -1e30f;
                for (int i = lane; i < deg; i += 64) m = fmaxf(m, sl[i]);
                for (int o = 32; o > 0; o >>= 1) m = fmaxf(m, __shfl_xor(m, o));
                float ss = 0.f;
                for (int i = lane; i < deg; i += 64) { float t = __expf(sl[i] - m); sl[i] = t; ss += t; }
                for (int o = 32; o > 0; o >>= 1) ss += __shfl_xor(ss, o);
                float r = 1.f / ss;
                for (int i = lane; i < deg; i += 64) sl[i] *= r;
            }
        }
        __syncthreads();
        if (tid < 128) {
            bool hi = tid >= 64;
            float acc = 0.f;
            for (int i = 0; i < deg; i++) {
                float a = hi ? sL1[i] : sL0[i];
                acc += a * (sXs[i] * sWl[tid] + sBl[tid]);
            }
            acc += sB1[tid];
            sH[tid] = fmaxf(acc, 0.f);
        }
        __syncthreads();
        // split-k GEMV: xl2 = bl2 + H @ Wl2 (256 threads, 64 k each)
        {
            int outc = tid & 127, k0 = (tid >> 7) << 6;
            float acc = 0.f;
            #pragma unroll 16
            for (int k = 0; k < 64; k++) acc += sH[k0 + k] * tld<F32>(Wl2, (k0 + k) * 128 + outc);
            sPartL[tid] = acc;
        }
        __syncthreads();
        if (tid < 128) xl2[bid * 128 + tid] = tld<F32>(bl2, tid) + sPartL[tid] + sPartL[tid + 128];
        if (s == tgt0) {
            __syncthreads();
            int outc = tid & 127, k0 = (tid >> 7) << 6;
            float acc = 0.f;
            #pragma unroll 16
            for (int k = 0; k < 64; k++) acc += sH[k0 + k] * tld<F32>(Wr2, (k0 + k) * 128 + outc);
            sPartL[tid] = acc;
            __syncthreads();
            if (tid < 128) xr2[tid] = tld<F32>(br2, tid) + sPartL[tid] + sPartL[tid + 128];
        }
        __syncthreads();
        __threadfence();
        if (tid == 0)
            __hip_atomic_fetch_add(&W[4], 1, __ATOMIC_RELEASE, __HIP_MEMORY_SCOPE_AGENT);
    } else if (bid == CAPS) {
        // ---------------- finisher: layer-2 + FC ----------------
        __shared__ float sXl2[CAPS * 129];   // stride 129: kills 32-way bank conflict
        __shared__ float sXr[128];
        __shared__ float sl0[CAP1], sl1[CAP1];
        __shared__ float sEaF[CAP1];
        __shared__ int   sslot[CAP1];
        __shared__ float semb[128];
        __shared__ int   sSf[CAPS];
        __shared__ float sWe2s[128], sAtt2s[128];
        __shared__ float sPartF[THR];

        // ===== pre-spin phase: only needs scan2 outputs (visible at launch) =====
        if (tid < ns) sSf[tid] = slist[tid];
        float b2vv = 0.f, bfcv = 0.f;
        if (tid < 128) {
            sWe2s[tid]  = tld<F32>(We2, tid);
            sAtt2s[tid] = tld<F32>(att2, tid);
            b2vv = tld<F32>(b2v, tid);
            bfcv = tld<F32>(bfc, tid);
        }
        __syncthreads();
        for (int e = tid; e < c1; e += THR) {
            int sv = l1src[e];
            int slot = 0;
            for (int j = 0; j < ns; j++) if (sSf[j] == sv) { slot = j; break; }
            sslot[e] = slot;
            sEaF[e] = l1ea[e];
        }
        // L2-warm Wfc while layer-1 blocks run (values kept alive, discarded)
        {
            float pf = 0.f;
            #pragma unroll 8
            for (int i = tid; i < 128 * 128; i += THR) pf += tld<F32>(Wfc, i);
            asm volatile("" :: "v"(pf));
        }
        // ===== spin: wait for all layer-1 blocks =====
        if (tid == 0) {
            while (__hip_atomic_load(&W[4], __ATOMIC_RELAXED, __HIP_MEMORY_SCOPE_AGENT) < ns)
                __builtin_amdgcn_s_sleep(8);
        }
        __syncthreads();
        __threadfence();
        // ===== bulk parallel load xl2/xr2 -> LDS (independent loads pipeline) =====
        for (int i = tid; i < ns * 128; i += THR)
            sXl2[(i >> 7) * 129 + (i & 127)] = ald_f(&xl2[i]);
        if (tid < 128) sXr[tid] = ald_f(&xr2[tid]);
        __syncthreads();
        // logits: one thread per edge, both heads, all-LDS
        for (int e = tid; e < c1; e += THR) {
            const float* row = &sXl2[sslot[e] * 129];
            float ev = sEaF[e];
            float l0 = 0.f, l1v = 0.f;
            #pragma unroll 8
            for (int c = 0; c < 128; c++) {
                float v = row[c] + sXr[c] + ev * sWe2s[c];
                v = v > 0.f ? v : NEG_SLOPE * v;
                float w = v * sAtt2s[c];
                if (c < 64) l0 += w; else l1v += w;
            }
            sl0[e] = l0; sl1[e] = l1v;
        }
        __syncthreads();
        // wave-parallel softmax: wave0 = head0, wave1 = head1
        {
            int lane = tid & 63, wv = tid >> 6;
            if (wv < 2) {
                float* sl = wv ? sl1 : sl0;
                float m = -1e30f;
                for (int e = lane; e < c1; e += 64) m = fmaxf(m, sl[e]);
                for (int o = 32; o > 0; o >>= 1) m = fmaxf(m, __shfl_xor(m, o));
                float ss = 0.f;
                for (int e = lane; e < c1; e += 64) { float t = __expf(sl[e] - m); sl[e] = t; ss += t; }
                for (int o = 32; o > 0; o >>= 1) ss += __shfl_xor(ss, o);
                float r = 1.f / ss;
                for (int e = lane; e < c1; e += 64) sl[e] *= r;
            }
        }
        __syncthreads();
        if (tid < 128) {
            bool hi = tid >= 64;
            float acc = b2vv;
            for (int e = 0; e < c1; e++) {
                float a = hi ? sl1[e] : sl0[e];
                acc += a * sXl2[sslot[e] * 129 + tid];
            }
            semb[tid] = acc;
        }
        __syncthreads();
        // FC split-k (Wfc is L2-warm from the pre-spin prefetch)
        {
            int outc = tid & 127, k0 = (tid >> 7) << 6;
            float acc = 0.f;
            #pragma unroll 16
            for (int k = 0; k < 64; k++) acc += semb[k0 + k] * tld<F32>(Wfc, (k0 + k) * 128 + outc);
            sPartF[tid] = acc;
        }
        __syncthreads();
        if (tid < 128) {
            float o = bfcv + sPartF[tid] + sPartF[tid + 128];
            if (F32) ((float*)out)[tid] = o;
            else     ((__hip_bfloat16*)out)[tid] = __float2bfloat16(o);
        }
    }
}

__global__ void __launch_bounds__(THR)
k_tail(const void* x, const int* tgt,
       const void* Wl1, const void* bl1, const void* Wr1, const void* br1,
       const void* We1, const void* att1, const void* b1,
       const void* Wl2, const void* bl2, const void* Wr2, const void* br2,
       const void* We2, const void* att2, const void* b2v,
       const void* Wfc, const void* bfc,
       void* out, int* W)
{
    int t = tgt[0];
    if (W[3]) tail_body<true >(x, t, Wl1, bl1, Wr1, br1, We1, att1, b1,
                               Wl2, bl2, Wr2, br2, We2, att2, b2v, Wfc, bfc, out, W);
    else      tail_body<false>(x, t, Wl1, bl1, Wr1, br1, We1, att1, b1,
                               Wl2, bl2, Wr2, br2, We2, att2, b2v, Wfc, bfc, out, W);
}

// ---------------------------------------------------------------------------
extern "C" void kernel_launch(void* const* d_in, const int* in_sizes, int n_in,
                              void* d_out, int out_size, void* d_ws, size_t ws_size,
                              hipStream_t stream) {
    const void* x    = d_in[0];
    const int*  eidx = (const int*)d_in[1];
    const void* eattr= d_in[2];
    const int*  tgt  = (const int*)d_in[3];
    const void* Wl1 = d_in[4],  *bl1 = d_in[5],  *Wr1 = d_in[6],  *br1 = d_in[7];
    const void* We1 = d_in[8],  *att1= d_in[9],  *b1  = d_in[10];
    const void* Wl2 = d_in[11], *bl2 = d_in[12], *Wr2 = d_in[13], *br2 = d_in[14];
    const void* We2 = d_in[15], *att2= d_in[16], *b2v = d_in[17];
    const void* Wfc = d_in[18], *bfc = d_in[19];

    int E = in_sizes[1] / 2;
    const int* src = eidx;
    const int* dst = eidx + E;
    int* W = (int*)d_ws;

    k_scan1<<<NB1, THR, 0, stream>>>(x, src, dst, eattr, tgt, E, W);
    k_scan2<<<NB2, THR, 0, stream>>>(src, dst, eattr, tgt, E, W);
    k_tail <<<NTAIL, THR, 0, stream>>>(x, tgt, Wl1, bl1, Wr1, br1, We1, att1, b1,
                                       Wl2, bl2, Wr2, br2, We2, att2, b2v,
                                       Wfc, bfc, d_out, W);
}

// Round 4
// 144.511 us; speedup vs baseline: 2.2637x; 1.0182x over previous
//
#include <hip/hip_runtime.h>
#include <hip/hip_bf16.h>

#define NEG_SLOPE 0.2f
#define THR    256   // threads per block
#define NB1    512   // scan1 blocks
#define NB2    512   // scan2 blocks
#define B1CAP  16    // per-block bucket cap, target edges (exp ~0.04/block)
#define B2CAP  32    // per-block bucket cap, S edges (exp ~1/block)
#define CAP1   512   // total edges into target (realistic ~21)
#define CAPS   64    // unique source nodes incl target (realistic ~21)
#define MAXDEG 256   // per-node in-degree cap in layer-1
#define NTAIL  (CAPS + 1)

// ws header: W[0]=c1 W[1]=ns W[3]=f32 W[4]=doneCnt W[5]=mean(bits)
#define OFF_PARTS  8
#define OFF_B1CNT  (OFF_PARTS + NB1)
#define OFF_B1SRC  (OFF_B1CNT + NB1)
#define OFF_B1EA   (OFF_B1SRC + NB1 * B1CAP)
#define OFF_B2CNT  (OFF_B1EA + NB1 * B1CAP)
#define OFF_B2SRC  (OFF_B2CNT + NB2)
#define OFF_B2DST  (OFF_B2SRC + NB2 * B2CAP)
#define OFF_B2EA   (OFF_B2DST + NB2 * B2CAP)
#define OFF_L1SRC  (OFF_B2EA + NB2 * B2CAP)
#define OFF_L1EA   (OFF_L1SRC + CAP1)
#define OFF_SLIST  (OFF_L1EA + CAP1)
#define OFF_XL2    (OFF_SLIST + CAPS)
#define OFF_XR2    (OFF_XL2 + CAPS * 128)

__device__ __forceinline__ float us2f(unsigned short s) {
    union { unsigned int u; float f; } c;
    c.u = ((unsigned int)s) << 16;
    return c.f;
}
template<bool F32>
__device__ __forceinline__ float tld(const void* p, int i) {
    if (F32) return ((const float*)p)[i];
    return us2f(((const unsigned short*)p)[i]);
}
__device__ __forceinline__ float ald_f(const float* p) {
    return __hip_atomic_load(p, __ATOMIC_RELAXED, __HIP_MEMORY_SCOPE_AGENT);
}

// ---------------------------------------------------------------------------
// K1: dtype detect (per-block) + bucketed scan for dst==target + ea partials.
// NOTE (R1 post-mortem): keep the 3-kernel structure. A fused single kernel
// with agent-scope acquire-poll grid barriers costs ~100 us PER BARRIER on
// gfx950 (cross-XCD coherence invalidation storm; measured 240 us fused vs
// ~25 us for 3 kernels + graph gaps). Kernel boundaries ARE the cheap barrier.
template<bool F32>
__device__ void scan1_body(const int* __restrict__ src, const int* __restrict__ dst,
                           const void* __restrict__ ea, int t, int E,
                           int* __restrict__ W) {
    __shared__ float sRed[4];
    __shared__ int   sCnt;
    __shared__ int   sIb[B1CAP];
    __shared__ float sFb[B1CAP];
    const int tid = threadIdx.x, bid = blockIdx.x;
    const int gid = bid * THR + tid, gs = NB1 * THR;
    const int E4 = E >> 2, rem = E & 3;
    float* parts = (float*)(W + OFF_PARTS);
    int*   b1cnt = W + OFF_B1CNT;
    int*   b1src = W + OFF_B1SRC;
    float* b1ea  = (float*)(W + OFF_B1EA);

    if (tid == 0) sCnt = 0;
    __syncthreads();
    float sum = 0.f;
    for (int j = gid; j < E4; j += gs) {
        int4 d4 = ((const int4*)dst)[j];
        float v0, v1, v2, v3;
        if (F32) {
            float4 e4 = ((const float4*)ea)[j];
            v0 = e4.x; v1 = e4.y; v2 = e4.z; v3 = e4.w;
        } else {
            ushort4 u4 = ((const ushort4*)ea)[j];
            v0 = us2f(u4.x); v1 = us2f(u4.y); v2 = us2f(u4.z); v3 = us2f(u4.w);
        }
        sum += (v0 + v1) + (v2 + v3);
        int base = 4 * j;
        if (d4.x == t) { int p = atomicAdd(&sCnt, 1); if (p < B1CAP) { sIb[p] = src[base+0]; sFb[p] = v0; } }
        if (d4.y == t) { int p = atomicAdd(&sCnt, 1); if (p < B1CAP) { sIb[p] = src[base+1]; sFb[p] = v1; } }
        if (d4.z == t) { int p = atomicAdd(&sCnt, 1); if (p < B1CAP) { sIb[p] = src[base+2]; sFb[p] = v2; } }
        if (d4.w == t) { int p = atomicAdd(&sCnt, 1); if (p < B1CAP) { sIb[p] = src[base+3]; sFb[p] = v3; } }
    }
    if (gid < rem) {
        int i = E4 * 4 + gid;
        float v = tld<F32>(ea, i);
        sum += v;
        if (dst[i] == t) { int p = atomicAdd(&sCnt, 1); if (p < B1CAP) { sIb[p] = src[i]; sFb[p] = v; } }
    }
    for (int o = 32; o > 0; o >>= 1) sum += __shfl_down(sum, o);
    if ((tid & 63) == 0) sRed[tid >> 6] = sum;
    __syncthreads();
    if (tid == 0) parts[bid] = sRed[0] + sRed[1] + sRed[2] + sRed[3];
    int bc = sCnt < B1CAP ? sCnt : B1CAP;
    if (tid == 0) b1cnt[bid] = bc;
    if (tid < bc) { b1src[bid * B1CAP + tid] = sIb[tid]; b1ea[bid * B1CAP + tid] = sFb[tid]; }
}

__global__ void __launch_bounds__(THR)
k_scan1(const void* __restrict__ x, const int* __restrict__ src,
        const int* __restrict__ dst, const void* __restrict__ ea,
        const int* __restrict__ tgt, int E, int* __restrict__ W) {
    __shared__ int sWeird;
    if (threadIdx.x == 0) sWeird = 0;
    __syncthreads();
    {
        const unsigned short* u = (const unsigned short*)x;
        int c = 0;
        for (int i = threadIdx.x; i < 2048; i += THR) {
            int e2 = (u[i] >> 7) & 0xFF;
            if (e2 == 0 || e2 >= 0xC0) c++;
        }
        for (int o = 32; o > 0; o >>= 1) c += __shfl_down(c, o);
        if ((threadIdx.x & 63) == 0) atomicAdd(&sWeird, c);
    }
    __syncthreads();
    bool f32 = sWeird >= 64;
    if (blockIdx.x == 0 && threadIdx.x == 0) W[3] = f32 ? 1 : 0;
    int t = tgt[0];
    if (f32) scan1_body<true >(src, dst, ea, t, E, W);
    else     scan1_body<false>(src, dst, ea, t, E, W);
}

// ---------------------------------------------------------------------------
// K2: every block builds its own membership list straight from the b1 buckets
//     (duplicates harmless) -> NO cross-block waiting. Bucket-scan edges whose
//     dst is in S. Block 0 afterwards runs the build step (compact l1, mean,
//     dedup slist) for the next kernel.
template<bool F32>
__device__ void scan2_body(const int* __restrict__ src, const int* __restrict__ dst,
                           const void* __restrict__ ea, int tgt0, int E,
                           int* __restrict__ W) {
    __shared__ int   sS[CAPS];
    __shared__ int   sNs, sCnt;
    __shared__ int   sIb[B2CAP], sIb2[B2CAP];
    __shared__ float sFb[B2CAP];
    __shared__ int   sPfx[THR];
    __shared__ float sRed[4];
    const int tid = threadIdx.x, bid = blockIdx.x;
    const int gid = bid * THR + tid, gs = NB2 * THR;
    const int E4 = E >> 2, rem = E & 3;
    float* parts = (float*)(W + OFF_PARTS);
    int*   b1cnt = W + OFF_B1CNT;
    int*   b1src = W + OFF_B1SRC;
    float* b1ea  = (float*)(W + OFF_B1EA);
    int*   b2cnt = W + OFF_B2CNT;
    int*   b2src = W + OFF_B2SRC;
    int*   b2dst = W + OFF_B2DST;
    float* b2ea  = (float*)(W + OFF_B2EA);
    int*   l1src = W + OFF_L1SRC;
    float* l1ea  = (float*)(W + OFF_L1EA);
    int*   slist = W + OFF_SLIST;

    // ---- membership list from raw buckets (incl. target itself) ----
    if (tid == 0) { sS[0] = tgt0; sNs = 1; sCnt = 0; }
    __syncthreads();
    for (int bk = tid; bk < NB1; bk += THR) {
        int c = b1cnt[bk]; if (c > B1CAP) c = B1CAP;
        for (int j = 0; j < c; j++) {
            int p = atomicAdd(&sNs, 1);
            if (p < CAPS) sS[p] = b1src[bk * B1CAP + j];
        }
    }
    __syncthreads();
    int ns = sNs < CAPS ? sNs : CAPS;

    #define CHECK(dv, idx)                                                     \
        do {                                                                   \
            for (int j_ = 0; j_ < ns; j_++) {                                  \
                if (sS[j_] == (dv)) {                                          \
                    int p_ = atomicAdd(&sCnt, 1);                              \
                    if (p_ < B2CAP) {                                          \
                        sIb[p_] = src[idx]; sIb2[p_] = (dv);                   \
                        sFb[p_] = tld<F32>(ea, idx);                           \
                    }                                                          \
                    break;                                                     \
                }                                                              \
            }                                                                  \
        } while (0)
    for (int j = gid; j < E4; j += gs) {
        int4 d4 = ((const int4*)dst)[j];
        int base = 4 * j;
        CHECK(d4.x, base + 0);
        CHECK(d4.y, base + 1);
        CHECK(d4.z, base + 2);
        CHECK(d4.w, base + 3);
    }
    if (gid < rem) { int i = E4 * 4 + gid; CHECK(dst[i], i); }
    #undef CHECK
    __syncthreads();
    int bc = sCnt < B2CAP ? sCnt : B2CAP;
    if (tid == 0) b2cnt[bid] = bc;
    if (tid < bc) {
        b2src[bid * B2CAP + tid] = sIb[tid];
        b2dst[bid * B2CAP + tid] = sIb2[tid];
        b2ea [bid * B2CAP + tid] = sFb[tid];
    }

    // ---- build step (block 0 only; consumed by the NEXT kernel) ----
    if (bid == 0) {
        __syncthreads();
        int c0  = b1cnt[2*tid];    if (c0  > B1CAP) c0  = B1CAP;
        int c1b = b1cnt[2*tid+1];  if (c1b > B1CAP) c1b = B1CAP;
        int c = c0 + c1b;
        sPfx[tid] = c;
        __syncthreads();
        for (int o = 1; o < THR; o <<= 1) {
            int v = (tid >= o) ? sPfx[tid - o] : 0;
            __syncthreads();
            sPfx[tid] += v;
            __syncthreads();
        }
        int base = sPfx[tid] - c;
        int c1tot = sPfx[THR - 1];
        for (int j = 0; j < c0; j++) {
            int p = base + j;
            if (p < CAP1 - 1) { l1src[p] = b1src[2*tid*B1CAP + j]; l1ea[p] = b1ea[2*tid*B1CAP + j]; }
        }
        for (int j = 0; j < c1b; j++) {
            int p = base + c0 + j;
            if (p < CAP1 - 1) { l1src[p] = b1src[(2*tid+1)*B1CAP + j]; l1ea[p] = b1ea[(2*tid+1)*B1CAP + j]; }
        }
        float s = parts[tid] + parts[tid + THR];
        for (int o = 32; o > 0; o >>= 1) s += __shfl_down(s, o);
        if ((tid & 63) == 0) sRed[tid >> 6] = s;
        __syncthreads();
        if (tid == 0) {
            float mean = (sRed[0] + sRed[1] + sRed[2] + sRed[3]) / (float)E;
            int c1 = c1tot < CAP1 - 1 ? c1tot : CAP1 - 1;
            l1src[c1] = tgt0; l1ea[c1] = mean;      // target self-loop
            c1++;
            int nsl = 0;                             // unique S (serial, ~21)
            for (int e = 0; e < c1; e++) {
                int sv = l1src[e];
                bool f = false;
                for (int j = 0; j < nsl; j++) if (sS[j] == sv) { f = true; break; }
                if (!f && nsl < CAPS) { sS[nsl] = sv; nsl++; }
            }
            for (int j = 0; j < nsl; j++) slist[j] = sS[j];
            W[0] = c1; W[1] = nsl; W[4] = 0;
            ((float*)W)[5] = mean;
        }
    }
}

__global__ void __launch_bounds__(THR)
k_scan2(const int* __restrict__ src, const int* __restrict__ dst,
        const void* __restrict__ ea, const int* __restrict__ tgt,
        int E, int* __restrict__ W) {
    int t = tgt[0];
    if (W[3]) scan2_body<true >(src, dst, ea, t, E, W);
    else      scan2_body<false>(src, dst, ea, t, E, W);
}

// ---------------------------------------------------------------------------
// K3: blocks 0..ns-1 = layer-1 per S-node; block CAPS = finisher (layer-2+FC).
// R2 post-mortem: k_tail was 45 us, pure latency chains (VALUBusy 0.1%).
// R3 fixes (45 -> <40): pre-spin hoisting + Wfc L2-warm + bulk LDS load of
// xl2/xr2 + wave-parallel softmax + split-k GEMVs.
// R4 fixes: (a) Wl2/Wr2 one-touch-per-line L2 prefetch issued at block start,
// sunk after the bucket gather (fetch overlaps the gather's latency chain —
// poison fill makes every iteration cold); (b) target block runs Wl2 and Wr2
// GEMVs in PARALLEL (half-block each, full-k) instead of two sequential
// split-k phases — the target block is the straggler the finisher spins on.
template<bool F32>
__device__ void tail_body(
    const void* __restrict__ x, int tgt0,
    const void* Wl1, const void* bl1, const void* Wr1, const void* br1,
    const void* We1, const void* att1, const void* b1,
    const void* Wl2, const void* bl2, const void* Wr2, const void* br2,
    const void* We2, const void* att2, const void* b2v,
    const void* Wfc, const void* bfc,
    void* __restrict__ out, int* __restrict__ W)
{
    const int tid = threadIdx.x, bid = blockIdx.x;
    int*   b2cnt = W + OFF_B2CNT;
    int*   b2src = W + OFF_B2SRC;
    int*   b2dst = W + OFF_B2DST;
    float* b2ea  = (float*)(W + OFF_B2EA);
    int*   l1src = W + OFF_L1SRC;
    float* l1ea  = (float*)(W + OFF_L1EA);
    int*   slist = W + OFF_SLIST;
    float* xl2   = (float*)(W + OFF_XL2);
    float* xr2   = (float*)(W + OFF_XR2);

    int ns = W[1]; if (ns > CAPS) ns = CAPS;
    int c1 = W[0]; if (c1 > CAP1) c1 = CAP1;
    float mean = ((float*)W)[5];

    if (bid < ns) {
        // ---------------- layer-1 for node s ----------------
        __shared__ float sWl[128], sBl[128], sWe[128], sAtt[128], sB1[128], sBase[128];
        __shared__ float sXs[MAXDEG], sEa2[MAXDEG], sL0[MAXDEG], sL1[MAXDEG], sH[128];
        __shared__ float sPartL[THR];
        __shared__ int sCnt;
        int s = slist[bid];
        // ---- L2-warm prefetch: one touch per 64B line of Wl2 (+Wr2 if tgt).
        // Loads are issued here; the value sink is AFTER the bucket gather so
        // the HBM fetch overlaps the gather's dependent-load chain.
        float pf = 0.f;
        for (int i = tid; i < 1024; i += THR) pf += tld<F32>(Wl2, i << 4);
        if (s == tgt0)
            for (int i = tid; i < 1024; i += THR) pf += tld<F32>(Wr2, i << 4);
        if (tid < 128) {
            sWl[tid] = tld<F32>(Wl1, tid);  sBl[tid] = tld<F32>(bl1, tid);
            sWe[tid] = tld<F32>(We1, tid);  sAtt[tid] = tld<F32>(att1, tid);
            sB1[tid] = tld<F32>(b1, tid);
            float xt = tld<F32>(x, s);
            sBase[tid] = xt * tld<F32>(Wr1, tid) + tld<F32>(br1, tid);
        }
        if (tid == 0) { sCnt = 1; sXs[0] = tld<F32>(x, s); sEa2[0] = mean; }  // self-loop
        __syncthreads();
        for (int bk = tid; bk < NB2; bk += THR) {
            int c = b2cnt[bk]; if (c > B2CAP) c = B2CAP;
            for (int j = 0; j < c; j++) {
                if (b2dst[bk * B2CAP + j] == s) {
                    int p = atomicAdd(&sCnt, 1);
                    if (p < MAXDEG) {
                        sXs[p] = tld<F32>(x, b2src[bk * B2CAP + j]);
                        sEa2[p] = b2ea[bk * B2CAP + j];
                    }
                }
            }
        }
        asm volatile("" :: "v"(pf));   // prefetch sink (keeps loads alive)
        __syncthreads();
        int deg = sCnt < MAXDEG ? sCnt : MAXDEG;
        // logits: 2 threads per edge (one per head), 64 channels each
        {
            int i0 = tid >> 1, half = tid & 1, c0 = half << 6;
            for (int i = i0; i < deg; i += 128) {
                float xs = sXs[i], eav = sEa2[i];
                float acc = 0.f;
                #pragma unroll 8
                for (int c2 = 0; c2 < 64; c2++) {
                    int c = c0 + c2;
                    float v = xs * sWl[c] + sBl[c] + sBase[c] + eav * sWe[c];
                    v = v > 0.f ? v : NEG_SLOPE * v;
                    acc += v * sAtt[c];
                }
                if (half == 0) sL0[i] = acc; else sL1[i] = acc;
            }
        }
        __syncthreads();
        // wave-parallel softmax: wave0 = head0, wave1 = head1
        {
            int lane = tid & 63, wv = tid >> 6;
            if (wv < 2) {
                float* sl = wv ? sL1 : sL0;
                float m = -1e30f;
                for (int i = lane; i < deg; i += 64) m = fmaxf(m, sl[i]);
                for (int o = 32; o > 0; o >>= 1) m = fmaxf(m, __shfl_xor(m, o));
                float ss = 0.f;
                for (int i = lane; i < deg; i += 64) { float t = __expf(sl[i] - m); sl[i] = t; ss += t; }
                for (int o = 32; o > 0; o >>= 1) ss += __shfl_xor(ss, o);
                float r = 1.f / ss;
                for (int i = lane; i < deg; i += 64) sl[i] *= r;
            }
        }
        __syncthreads();
        if (tid < 128) {
            bool hi = tid >= 64;
            float acc = 0.f;
            for (int i = 0; i < deg; i++) {
                float a = hi ? sL1[i] : sL0[i];
                acc += a * (sXs[i] * sWl[tid] + sBl[tid]);
            }
            acc += sB1[tid];
            sH[tid] = fmaxf(acc, 0.f);
        }
        __syncthreads();
        if (s != tgt0) {
            // split-k GEMV: xl2 = bl2 + H @ Wl2 (256 threads, 64 k each, L2-warm)
            int outc = tid & 127, k0 = (tid >> 7) << 6;
            float acc = 0.f;
            #pragma unroll 16
            for (int k = 0; k < 64; k++) acc += sH[k0 + k] * tld<F32>(Wl2, (k0 + k) * 128 + outc);
            sPartL[tid] = acc;
            __syncthreads();
            if (tid < 128) xl2[bid * 128 + tid] = tld<F32>(bl2, tid) + sPartL[tid] + sPartL[tid + 128];
        } else {
            // target block: Wl2 and Wr2 GEMVs in parallel (half-block each)
            int outc = tid & 127;
            bool lo = tid < 128;
            const void* Wm = lo ? Wl2 : Wr2;
            float acc = lo ? tld<F32>(bl2, outc) : tld<F32>(br2, outc);
            #pragma unroll 16
            for (int k = 0; k < 128; k++) acc += sH[k] * tld<F32>(Wm, k * 128 + outc);
            if (lo) xl2[bid * 128 + outc] = acc;
            else    xr2[outc] = acc;
        }
        __syncthreads();
        __threadfence();
        if (tid == 0)
            __hip_atomic_fetch_add(&W[4], 1, __ATOMIC_RELEASE, __HIP_MEMORY_SCOPE_AGENT);
    } else if (bid == CAPS) {
        // ---------------- finisher: layer-2 + FC ----------------
        __shared__ float sXl2[CAPS * 129];   // stride 129: kills 32-way bank conflict
        __shared__ float sXr[128];
        __shared__ float sl0[CAP1], sl1[CAP1];
        __shared__ float sEaF[CAP1];
        __shared__ int   sslot[CAP1];
        __shared__ float semb[128];
        __shared__ int   sSf[CAPS];
        __shared__ float sWe2s[128], sAtt2s[128];
        __shared__ float sPartF[THR];

        // ===== pre-spin phase: only needs scan2 outputs (visible at launch) =====
        if (tid < ns) sSf[tid] = slist[tid];
        float b2vv = 0.f, bfcv = 0.f;
        if (tid < 128) {
            sWe2s[tid]  = tld<F32>(We2, tid);
            sAtt2s[tid] = tld<F32>(att2, tid);
            b2vv = tld<F32>(b2v, tid);
            bfcv = tld<F32>(bfc, tid);
        }
        __syncthreads();
        for (int e = tid; e < c1; e += THR) {
            int sv = l1src[e];
            int slot = 0;
            for (int j = 0; j < ns; j++) if (sSf[j] == sv) { slot = j; break; }
            sslot[e] = slot;
            sEaF[e] = l1ea[e];
        }
        // L2-warm Wfc while layer-1 blocks run (values kept alive, discarded)
        {
            float pf = 0.f;
            #pragma unroll 8
            for (int i = tid; i < 128 * 128; i += THR) pf += tld<F32>(Wfc, i);
            asm volatile("" :: "v"(pf));
        }
        // ===== spin: wait for all layer-1 blocks =====
        if (tid == 0) {
            while (__hip_atomic_load(&W[4], __ATOMIC_RELAXED, __HIP_MEMORY_SCOPE_AGENT) < ns)
                __builtin_amdgcn_s_sleep(8);
        }
        __syncthreads();
        __threadfence();
        // ===== bulk parallel load xl2/xr2 -> LDS (independent loads pipeline) =====
        for (int i = tid; i < ns * 128; i += THR)
            sXl2[(i >> 7) * 129 + (i & 127)] = ald_f(&xl2[i]);
        if (tid < 128) sXr[tid] = ald_f(&xr2[tid]);
        __syncthreads();
        // logits: one thread per edge, both heads, all-LDS
        for (int e = tid; e < c1; e += THR) {
            const float* row = &sXl2[sslot[e] * 129];
            float ev = sEaF[e];
            float l0 = 0.f, l1v = 0.f;
            #pragma unroll 8
            for (int c = 0; c < 128; c++) {
                float v = row[c] + sXr[c] + ev * sWe2s[c];
                v = v > 0.f ? v : NEG_SLOPE * v;
                float w = v * sAtt2s[c];
                if (c < 64) l0 += w; else l1v += w;
            }
            sl0[e] = l0; sl1[e] = l1v;
        }
        __syncthreads();
        // wave-parallel softmax: wave0 = head0, wave1 = head1
        {
            int lane = tid & 63, wv = tid >> 6;
            if (wv < 2) {
                float* sl = wv ? sl1 : sl0;
                float m = -1e30f;
                for (int e = lane; e < c1; e += 64) m = fmaxf(m, sl[e]);
                for (int o = 32; o > 0; o >>= 1) m = fmaxf(m, __shfl_xor(m, o));
                float ss = 0.f;
                for (int e = lane; e < c1; e += 64) { float t = __expf(sl[e] - m); sl[e] = t; ss += t; }
                for (int o = 32; o > 0; o >>= 1) ss += __shfl_xor(ss, o);
                float r = 1.f / ss;
                for (int e = lane; e < c1; e += 64) sl[e] *= r;
            }
        }
        __syncthreads();
        if (tid < 128) {
            bool hi = tid >= 64;
            float acc = b2vv;
            for (int e = 0; e < c1; e++) {
                float a = hi ? sl1[e] : sl0[e];
                acc += a * sXl2[sslot[e] * 129 + tid];
            }
            semb[tid] = acc;
        }
        __syncthreads();
        // FC split-k (Wfc is L2-warm from the pre-spin prefetch)
        {
            int outc = tid & 127, k0 = (tid >> 7) << 6;
            float acc = 0.f;
            #pragma unroll 16
            for (int k = 0; k < 64; k++) acc += semb[k0 + k] * tld<F32>(Wfc, (k0 + k) * 128 + outc);
            sPartF[tid] = acc;
        }
        __syncthreads();
        if (tid < 128) {
            float o = bfcv + sPartF[tid] + sPartF[tid + 128];
            if (F32) ((float*)out)[tid] = o;
            else     ((__hip_bfloat16*)out)[tid] = __float2bfloat16(o);
        }
    }
}

__global__ void __launch_bounds__(THR)
k_tail(const void* x, const int* tgt,
       const void* Wl1, const void* bl1, const void* Wr1, const void* br1,
       const void* We1, const void* att1, const void* b1,
       const void* Wl2, const void* bl2, const void* Wr2, const void* br2,
       const void* We2, const void* att2, const void* b2v,
       const void* Wfc, const void* bfc,
       void* out, int* W)
{
    int t = tgt[0];
    if (W[3]) tail_body<true >(x, t, Wl1, bl1, Wr1, br1, We1, att1, b1,
                               Wl2, bl2, Wr2, br2, We2, att2, b2v, Wfc, bfc, out, W);
    else      tail_body<false>(x, t, Wl1, bl1, Wr1, br1, We1, att1, b1,
                               Wl2, bl2, Wr2, br2, We2, att2, b2v, Wfc, bfc, out, W);
}

// ---------------------------------------------------------------------------
extern "C" void kernel_launch(void* const* d_in, const int* in_sizes, int n_in,
                              void* d_out, int out_size, void* d_ws, size_t ws_size,
                              hipStream_t stream) {
    const void* x    = d_in[0];
    const int*  eidx = (const int*)d_in[1];
    const void* eattr= d_in[2];
    const int*  tgt  = (const int*)d_in[3];
    const void* Wl1 = d_in[4],  *bl1 = d_in[5],  *Wr1 = d_in[6],  *br1 = d_in[7];
    const void* We1 = d_in[8],  *att1= d_in[9],  *b1  = d_in[10];
    const void* Wl2 = d_in[11], *bl2 = d_in[12], *Wr2 = d_in[13], *br2 = d_in[14];
    const void* We2 = d_in[15], *att2= d_in[16], *b2v = d_in[17];
    const void* Wfc = d_in[18], *bfc = d_in[19];

    int E = in_sizes[1] / 2;
    const int* src = eidx;
    const int* dst = eidx + E;
    int* W = (int*)d_ws;

    k_scan1<<<NB1, THR, 0, stream>>>(x, src, dst, eattr, tgt, E, W);
    k_scan2<<<NB2, THR, 0, stream>>>(src, dst, eattr, tgt, E, W);
    k_tail <<<NTAIL, THR, 0, stream>>>(x, tgt, Wl1, bl1, Wr1, br1, We1, att1, b1,
                                       Wl2, bl2, Wr2, br2, We2, att2, b2v,
                                       Wfc, bfc, d_out, W);
}

// Round 6
// 141.034 us; speedup vs baseline: 2.3195x; 1.0247x over previous
//
#include <hip/hip_runtime.h>
#include <hip/hip_bf16.h>

#define NEG_SLOPE 0.2f
#define THR    256   // threads per block
#define NB1    1024  // scan1 blocks: exactly ONE int4 per thread (1-round latency)
#define NB2    1024  // scan2 blocks: same
#define B1CAP  16    // per-block bucket cap, target edges
#define CAP1   512   // total edges into target (realistic ~21)
#define CAPS   64    // unique source nodes incl target (realistic ~21)
#define CAPL2  4096  // compact 2-hop edge list cap (realistic ~450)
#define MAXDEG 256   // per-node in-degree cap in layer-1
#define NTAIL  (CAPS + 1)

// ws header: W[0]=c1 W[1]=ns W[3]=f32 W[4]=doneCnt W[5]=mean(bits) W[6]=l2cnt
#define OFF_PARTS  8
#define OFF_B1CNT  (OFF_PARTS + NB1)
#define OFF_B1SRC  (OFF_B1CNT + NB1)
#define OFF_B1EA   (OFF_B1SRC + NB1 * B1CAP)
#define OFF_L2S    (OFF_B1EA + NB1 * B1CAP)
#define OFF_L2D    (OFF_L2S + CAPL2)
#define OFF_L2E    (OFF_L2D + CAPL2)
#define OFF_L1SRC  (OFF_L2E + CAPL2)
#define OFF_L1EA   (OFF_L1SRC + CAP1)
#define OFF_SLIST  (OFF_L1EA + CAP1)
#define OFF_XL2    (OFF_SLIST + CAPS)
#define OFF_XR2    (OFF_XL2 + CAPS * 128)

__device__ __forceinline__ float us2f(unsigned short s) {
    union { unsigned int u; float f; } c;
    c.u = ((unsigned int)s) << 16;
    return c.f;
}
template<bool F32>
__device__ __forceinline__ float tld(const void* p, int i) {
    if (F32) return ((const float*)p)[i];
    return us2f(((const unsigned short*)p)[i]);
}
__device__ __forceinline__ float ald_f(const float* p) {
    return __hip_atomic_load(p, __ATOMIC_RELAXED, __HIP_MEMORY_SCOPE_AGENT);
}

// ---------------------------------------------------------------------------
// K1: dtype detect + bucketed scan for dst==target + ea partials.
// NOTE (R1 post-mortem): keep the 3-kernel structure. A fused single kernel
// with agent-scope acquire-poll grid barriers costs ~100 us PER BARRIER on
// gfx950 (cross-XCD coherence invalidation storm; measured 240 us fused vs
// ~25 us split). Kernel boundaries ARE the cheap barrier on this chip.
// R5: NB1=1024 -> each thread does exactly ONE int4 iteration (one cold-HBM
// round instead of two sequential ones). Also zeroes W[6] for scan2's
// compact-list counter (same-iteration init; poison-safe via kernel boundary).
template<bool F32>
__device__ void scan1_body(const int* __restrict__ src, const int* __restrict__ dst,
                           const void* __restrict__ ea, int t, int E,
                           int* __restrict__ W) {
    __shared__ float sRed[4];
    __shared__ int   sCnt;
    __shared__ int   sIb[B1CAP];
    __shared__ float sFb[B1CAP];
    const int tid = threadIdx.x, bid = blockIdx.x;
    const int gid = bid * THR + tid, gs = NB1 * THR;
    const int E4 = E >> 2, rem = E & 3;
    float* parts = (float*)(W + OFF_PARTS);
    int*   b1cnt = W + OFF_B1CNT;
    int*   b1src = W + OFF_B1SRC;
    float* b1ea  = (float*)(W + OFF_B1EA);

    if (tid == 0) sCnt = 0;
    __syncthreads();
    float sum = 0.f;
    for (int j = gid; j < E4; j += gs) {
        int4 d4 = ((const int4*)dst)[j];
        float v0, v1, v2, v3;
        if (F32) {
            float4 e4 = ((const float4*)ea)[j];
            v0 = e4.x; v1 = e4.y; v2 = e4.z; v3 = e4.w;
        } else {
            ushort4 u4 = ((const ushort4*)ea)[j];
            v0 = us2f(u4.x); v1 = us2f(u4.y); v2 = us2f(u4.z); v3 = us2f(u4.w);
        }
        sum += (v0 + v1) + (v2 + v3);
        int base = 4 * j;
        if (d4.x == t) { int p = atomicAdd(&sCnt, 1); if (p < B1CAP) { sIb[p] = src[base+0]; sFb[p] = v0; } }
        if (d4.y == t) { int p = atomicAdd(&sCnt, 1); if (p < B1CAP) { sIb[p] = src[base+1]; sFb[p] = v1; } }
        if (d4.z == t) { int p = atomicAdd(&sCnt, 1); if (p < B1CAP) { sIb[p] = src[base+2]; sFb[p] = v2; } }
        if (d4.w == t) { int p = atomicAdd(&sCnt, 1); if (p < B1CAP) { sIb[p] = src[base+3]; sFb[p] = v3; } }
    }
    if (gid < rem) {
        int i = E4 * 4 + gid;
        float v = tld<F32>(ea, i);
        sum += v;
        if (dst[i] == t) { int p = atomicAdd(&sCnt, 1); if (p < B1CAP) { sIb[p] = src[i]; sFb[p] = v; } }
    }
    for (int o = 32; o > 0; o >>= 1) sum += __shfl_down(sum, o);
    if ((tid & 63) == 0) sRed[tid >> 6] = sum;
    __syncthreads();
    if (tid == 0) parts[bid] = sRed[0] + sRed[1] + sRed[2] + sRed[3];
    int bc = sCnt < B1CAP ? sCnt : B1CAP;
    if (tid == 0) b1cnt[bid] = bc;
    if (tid < bc) { b1src[bid * B1CAP + tid] = sIb[tid]; b1ea[bid * B1CAP + tid] = sFb[tid]; }
}

__global__ void __launch_bounds__(THR)
k_scan1(const void* __restrict__ x, const int* __restrict__ src,
        const int* __restrict__ dst, const void* __restrict__ ea,
        const int* __restrict__ tgt, int E, int* __restrict__ W) {
    __shared__ int sWeird;
    if (threadIdx.x == 0) sWeird = 0;
    __syncthreads();
    {
        const unsigned short* u = (const unsigned short*)x;
        int c = 0;
        for (int i = threadIdx.x; i < 2048; i += THR) {
            int e2 = (u[i] >> 7) & 0xFF;
            if (e2 == 0 || e2 >= 0xC0) c++;
        }
        for (int o = 32; o > 0; o >>= 1) c += __shfl_down(c, o);
        if ((threadIdx.x & 63) == 0) atomicAdd(&sWeird, c);
    }
    __syncthreads();
    bool f32 = sWeird >= 64;
    if (blockIdx.x == 0 && threadIdx.x == 0) { W[3] = f32 ? 1 : 0; W[6] = 0; }
    int t = tgt[0];
    if (f32) scan1_body<true >(src, dst, ea, t, E, W);
    else     scan1_body<false>(src, dst, ea, t, E, W);
}

// ---------------------------------------------------------------------------
// K2: every block builds its own membership list from the b1 buckets
//     (duplicates harmless), scans its edge slice for dst in S, and appends
//     hits to a GLOBAL COMPACT LIST via one atomicAdd on W[6] (R5: replaces
//     per-block b2 buckets -> tail gather becomes a coalesced list read).
//     Block 0 afterwards runs the build step (compact l1, mean, dedup slist).
template<bool F32>
__device__ void scan2_body(const int* __restrict__ src, const int* __restrict__ dst,
                           const void* __restrict__ ea, int tgt0, int E,
                           int* __restrict__ W) {
    __shared__ int   sS[CAPS];
    __shared__ int   sNs, sCnt, sBase;
    __shared__ int   sIb[32], sIb2[32];
    __shared__ float sFb[32];
    __shared__ int   sPfx[THR];
    __shared__ float sRed[4];
    const int tid = threadIdx.x, bid = blockIdx.x;
    const int gid = bid * THR + tid, gs = NB2 * THR;
    const int E4 = E >> 2, rem = E & 3;
    float* parts = (float*)(W + OFF_PARTS);
    int*   b1cnt = W + OFF_B1CNT;
    int*   b1src = W + OFF_B1SRC;
    float* b1ea  = (float*)(W + OFF_B1EA);
    int*   l2s   = W + OFF_L2S;
    int*   l2d   = W + OFF_L2D;
    float* l2e   = (float*)(W + OFF_L2E);
    int*   l1src = W + OFF_L1SRC;
    float* l1ea  = (float*)(W + OFF_L1EA);
    int*   slist = W + OFF_SLIST;

    // ---- membership list from raw buckets (incl. target itself) ----
    if (tid == 0) { sS[0] = tgt0; sNs = 1; sCnt = 0; }
    __syncthreads();
    for (int bk = tid; bk < NB1; bk += THR) {
        int c = b1cnt[bk]; if (c > B1CAP) c = B1CAP;
        for (int j = 0; j < c; j++) {
            int p = atomicAdd(&sNs, 1);
            if (p < CAPS) sS[p] = b1src[bk * B1CAP + j];
        }
    }
    __syncthreads();
    int ns = sNs < CAPS ? sNs : CAPS;

    #define CHECK(dv, idx)                                                     \
        do {                                                                   \
            for (int j_ = 0; j_ < ns; j_++) {                                  \
                if (sS[j_] == (dv)) {                                          \
                    int p_ = atomicAdd(&sCnt, 1);                              \
                    if (p_ < 32) {                                             \
                        sIb[p_] = src[idx]; sIb2[p_] = (dv);                   \
                        sFb[p_] = tld<F32>(ea, idx);                           \
                    }                                                          \
                    break;                                                     \
                }                                                              \
            }                                                                  \
        } while (0)
    for (int j = gid; j < E4; j += gs) {
        int4 d4 = ((const int4*)dst)[j];
        int base = 4 * j;
        CHECK(d4.x, base + 0);
        CHECK(d4.y, base + 1);
        CHECK(d4.z, base + 2);
        CHECK(d4.w, base + 3);
    }
    if (gid < rem) { int i = E4 * 4 + gid; CHECK(dst[i], i); }
    #undef CHECK
    __syncthreads();
    int bc = sCnt < 32 ? sCnt : 32;
    if (tid == 0) sBase = bc > 0 ? atomicAdd(&W[6], bc) : 0;
    __syncthreads();
    if (tid < bc) {
        int p = sBase + tid;
        if (p < CAPL2) { l2s[p] = sIb[tid]; l2d[p] = sIb2[tid]; l2e[p] = sFb[tid]; }
    }

    // ---- build step (block 0 only; consumed by the NEXT kernel) ----
    if (bid == 0) {
        __syncthreads();
        int ca = b1cnt[4*tid];     if (ca > B1CAP) ca = B1CAP;
        int cb = b1cnt[4*tid+1];   if (cb > B1CAP) cb = B1CAP;
        int cc = b1cnt[4*tid+2];   if (cc > B1CAP) cc = B1CAP;
        int cd = b1cnt[4*tid+3];   if (cd > B1CAP) cd = B1CAP;
        int c = ca + cb + cc + cd;
        sPfx[tid] = c;
        __syncthreads();
        for (int o = 1; o < THR; o <<= 1) {
            int v = (tid >= o) ? sPfx[tid - o] : 0;
            __syncthreads();
            sPfx[tid] += v;
            __syncthreads();
        }
        int p = sPfx[tid] - c;
        int c1tot = sPfx[THR - 1];
        int cnts[4] = {ca, cb, cc, cd};
        for (int k = 0; k < 4; k++) {
            int bk = 4*tid + k;
            for (int j = 0; j < cnts[k]; j++) {
                if (p < CAP1 - 1) { l1src[p] = b1src[bk*B1CAP + j]; l1ea[p] = b1ea[bk*B1CAP + j]; }
                p++;
            }
        }
        float s = parts[tid] + parts[tid + THR] + parts[tid + 2*THR] + parts[tid + 3*THR];
        for (int o = 32; o > 0; o >>= 1) s += __shfl_down(s, o);
        if ((tid & 63) == 0) sRed[tid >> 6] = s;
        __syncthreads();
        if (tid == 0) {
            float mean = (sRed[0] + sRed[1] + sRed[2] + sRed[3]) / (float)E;
            int c1 = c1tot < CAP1 - 1 ? c1tot : CAP1 - 1;
            l1src[c1] = tgt0; l1ea[c1] = mean;      // target self-loop
            c1++;
            int nsl = 0;                             // unique S (serial, ~21)
            for (int e = 0; e < c1; e++) {
                int sv = l1src[e];
                bool f = false;
                for (int j = 0; j < nsl; j++) if (sS[j] == sv) { f = true; break; }
                if (!f && nsl < CAPS) { sS[nsl] = sv; nsl++; }
            }
            for (int j = 0; j < nsl; j++) slist[j] = sS[j];
            W[0] = c1; W[1] = nsl; W[4] = 0;
            ((float*)W)[5] = mean;
        }
    }
}

__global__ void __launch_bounds__(THR)
k_scan2(const int* __restrict__ src, const int* __restrict__ dst,
        const void* __restrict__ ea, const int* __restrict__ tgt,
        int E, int* __restrict__ W) {
    int t = tgt[0];
    if (W[3]) scan2_body<true >(src, dst, ea, t, E, W);
    else      scan2_body<false>(src, dst, ea, t, E, W);
}

// ---------------------------------------------------------------------------
// K3: blocks 0..ns-1 = layer-1 per S-node; block CAPS = finisher (layer-2+FC).
// R2: was 45 us of latency chains. R3: pre-spin hoisting + Wfc L2-warm +
// bulk LDS xl2 load + wave-parallel softmax + split-k GEMVs (-> <40).
// R4: Wl2/Wr2 L2 prefetch overlapping the gather; target block runs Wl2+Wr2
// GEMVs in parallel (it's the straggler the finisher spins on).
// R5: gather reads the compact l2 list (coalesced, depth-3 chain) instead of
// sweeping 512 scattered buckets (depth-4).
template<bool F32>
__device__ void tail_body(
    const void* __restrict__ x, int tgt0,
    const void* Wl1, const void* bl1, const void* Wr1, const void* br1,
    const void* We1, const void* att1, const void* b1,
    const void* Wl2, const void* bl2, const void* Wr2, const void* br2,
    const void* We2, const void* att2, const void* b2v,
    const void* Wfc, const void* bfc,
    void* __restrict__ out, int* __restrict__ W)
{
    const int tid = threadIdx.x, bid = blockIdx.x;
    int*   l2s   = W + OFF_L2S;
    int*   l2d   = W + OFF_L2D;
    float* l2e   = (float*)(W + OFF_L2E);
    int*   l1src = W + OFF_L1SRC;
    float* l1ea  = (float*)(W + OFF_L1EA);
    int*   slist = W + OFF_SLIST;
    float* xl2   = (float*)(W + OFF_XL2);
    float* xr2   = (float*)(W + OFF_XR2);

    int ns = W[1]; if (ns > CAPS) ns = CAPS;
    int c1 = W[0]; if (c1 > CAP1) c1 = CAP1;
    float mean = ((float*)W)[5];

    if (bid < ns) {
        // ---------------- layer-1 for node s ----------------
        __shared__ float sWl[128], sBl[128], sWe[128], sAtt[128], sB1[128], sBase[128];
        __shared__ float sXs[MAXDEG], sEa2[MAXDEG], sL0[MAXDEG], sL1[MAXDEG], sH[128];
        __shared__ float sPartL[THR];
        __shared__ int sCnt;
        int s = slist[bid];
        int cnt2 = W[6]; if (cnt2 > CAPL2) cnt2 = CAPL2;
        // ---- L2-warm prefetch: one touch per 64B line of Wl2 (+Wr2 if tgt).
        // Loads issued here; value sink AFTER the gather so the HBM fetch
        // overlaps the gather's dependent-load chain (poison keeps L2 cold).
        float pf = 0.f;
        for (int i = tid; i < 1024; i += THR) pf += tld<F32>(Wl2, i << 4);
        if (s == tgt0)
            for (int i = tid; i < 1024; i += THR) pf += tld<F32>(Wr2, i << 4);
        if (tid < 128) {
            sWl[tid] = tld<F32>(Wl1, tid);  sBl[tid] = tld<F32>(bl1, tid);
            sWe[tid] = tld<F32>(We1, tid);  sAtt[tid] = tld<F32>(att1, tid);
            sB1[tid] = tld<F32>(b1, tid);
            float xt = tld<F32>(x, s);
            sBase[tid] = xt * tld<F32>(Wr1, tid) + tld<F32>(br1, tid);
        }
        if (tid == 0) { sCnt = 1; sXs[0] = tld<F32>(x, s); sEa2[0] = mean; }  // self-loop
        __syncthreads();
        // gather from compact list: coalesced read, depth-3 chain
        for (int e = tid; e < cnt2; e += THR) {
            if (l2d[e] == s) {
                int p = atomicAdd(&sCnt, 1);
                if (p < MAXDEG) {
                    sXs[p] = tld<F32>(x, l2s[e]);
                    sEa2[p] = l2e[e];
                }
            }
        }
        asm volatile("" :: "v"(pf));   // prefetch sink (keeps loads alive)
        __syncthreads();
        int deg = sCnt < MAXDEG ? sCnt : MAXDEG;
        // logits: 2 threads per edge (one per head), 64 channels each
        {
            int i0 = tid >> 1, half = tid & 1, c0 = half << 6;
            for (int i = i0; i < deg; i += 128) {
                float xs = sXs[i], eav = sEa2[i];
                float acc = 0.f;
                #pragma unroll 8
                for (int c2 = 0; c2 < 64; c2++) {
                    int c = c0 + c2;
                    float v = xs * sWl[c] + sBl[c] + sBase[c] + eav * sWe[c];
                    v = v > 0.f ? v : NEG_SLOPE * v;
                    acc += v * sAtt[c];
                }
                if (half == 0) sL0[i] = acc; else sL1[i] = acc;
            }
        }
        __syncthreads();
        // wave-parallel softmax: wave0 = head0, wave1 = head1
        {
            int lane = tid & 63, wv = tid >> 6;
            if (wv < 2) {
                float* sl = wv ? sL1 : sL0;
                float m = -1e30f;
                for (int i = lane; i < deg; i += 64) m = fmaxf(m, sl[i]);
                for (int o = 32; o > 0; o >>= 1) m = fmaxf(m, __shfl_xor(m, o));
                float ss = 0.f;
                for (int i = lane; i < deg; i += 64) { float t = __expf(sl[i] - m); sl[i] = t; ss += t; }
                for (int o = 32; o > 0; o >>= 1) ss += __shfl_xor(ss, o);
                float r = 1.f / ss;
                for (int i = lane; i < deg; i += 64) sl[i] *= r;
            }
        }
        __syncthreads();
        if (tid < 128) {
            bool hi = tid >= 64;
            float acc = 0.f;
            for (int i = 0; i < deg; i++) {
                float a = hi ? sL1[i] : sL0[i];
                acc += a * (sXs[i] * sWl[tid] + sBl[tid]);
            }
            acc += sB1[tid];
            sH[tid] = fmaxf(acc, 0.f);
        }
        __syncthreads();
        if (s != tgt0) {
            // split-k GEMV: xl2 = bl2 + H @ Wl2 (256 threads, 64 k each, L2-warm)
            int outc = tid & 127, k0 = (tid >> 7) << 6;
            float acc = 0.f;
            #pragma unroll 16
            for (int k = 0; k < 64; k++) acc += sH[k0 + k] * tld<F32>(Wl2, (k0 + k) * 128 + outc);
            sPartL[tid] = acc;
            __syncthreads();
            if (tid < 128) xl2[bid * 128 + tid] = tld<F32>(bl2, tid) + sPartL[tid] + sPartL[tid + 128];
        } else {
            // target block: Wl2 and Wr2 GEMVs in parallel (half-block each)
            int outc = tid & 127;
            bool lo = tid < 128;
            const void* Wm = lo ? Wl2 : Wr2;
            float acc = lo ? tld<F32>(bl2, outc) : tld<F32>(br2, outc);
            #pragma unroll 16
            for (int k = 0; k < 128; k++) acc += sH[k] * tld<F32>(Wm, k * 128 + outc);
            if (lo) xl2[bid * 128 + outc] = acc;
            else    xr2[outc] = acc;
        }
        __syncthreads();
        __threadfence();
        if (tid == 0)
            __hip_atomic_fetch_add(&W[4], 1, __ATOMIC_RELEASE, __HIP_MEMORY_SCOPE_AGENT);
    } else if (bid == CAPS) {
        // ---------------- finisher: layer-2 + FC ----------------
        __shared__ float sXl2[CAPS * 129];   // stride 129: kills 32-way bank conflict
        __shared__ float sXr[128];
        __shared__ float sl0[CAP1], sl1[CAP1];
        __shared__ float sEaF[CAP1];
        __shared__ int   sslot[CAP1];
        __shared__ float semb[128];
        __shared__ int   sSf[CAPS];
        __shared__ float sWe2s[128], sAtt2s[128];
        __shared__ float sPartF[THR];

        // ===== pre-spin phase: only needs scan2 outputs (visible at launch) =====
        if (tid < ns) sSf[tid] = slist[tid];
        float b2vv = 0.f, bfcv = 0.f;
        if (tid < 128) {
            sWe2s[tid]  = tld<F32>(We2, tid);
            sAtt2s[tid] = tld<F32>(att2, tid);
            b2vv = tld<F32>(b2v, tid);
            bfcv = tld<F32>(bfc, tid);
        }
        __syncthreads();
        for (int e = tid; e < c1; e += THR) {
            int sv = l1src[e];
            int slot = 0;
            for (int j = 0; j < ns; j++) if (sSf[j] == sv) { slot = j; break; }
            sslot[e] = slot;
            sEaF[e] = l1ea[e];
        }
        // L2-warm Wfc while layer-1 blocks run (values kept alive, discarded)
        {
            float pf = 0.f;
            #pragma unroll 8
            for (int i = tid; i < 128 * 128; i += THR) pf += tld<F32>(Wfc, i);
            asm volatile("" :: "v"(pf));
        }
        // ===== spin: wait for all layer-1 blocks =====
        if (tid == 0) {
            while (__hip_atomic_load(&W[4], __ATOMIC_RELAXED, __HIP_MEMORY_SCOPE_AGENT) < ns)
                __builtin_amdgcn_s_sleep(8);
        }
        __syncthreads();
        __threadfence();
        // ===== bulk parallel load xl2/xr2 -> LDS (independent loads pipeline) =====
        for (int i = tid; i < ns * 128; i += THR)
            sXl2[(i >> 7) * 129 + (i & 127)] = ald_f(&xl2[i]);
        if (tid < 128) sXr[tid] = ald_f(&xr2[tid]);
        __syncthreads();
        // logits: one thread per edge, both heads, all-LDS
        for (int e = tid; e < c1; e += THR) {
            const float* row = &sXl2[sslot[e] * 129];
            float ev = sEaF[e];
            float l0 = 0.f, l1v = 0.f;
            #pragma unroll 8
            for (int c = 0; c < 128; c++) {
                float v = row[c] + sXr[c] + ev * sWe2s[c];
                v = v > 0.f ? v : NEG_SLOPE * v;
                float w = v * sAtt2s[c];
                if (c < 64) l0 += w; else l1v += w;
            }
            sl0[e] = l0; sl1[e] = l1v;
        }
        __syncthreads();
        // wave-parallel softmax: wave0 = head0, wave1 = head1
        {
            int lane = tid & 63, wv = tid >> 6;
            if (wv < 2) {
                float* sl = wv ? sl1 : sl0;
                float m = -1e30f;
                for (int e = lane; e < c1; e += 64) m = fmaxf(m, sl[e]);
                for (int o = 32; o > 0; o >>= 1) m = fmaxf(m, __shfl_xor(m, o));
                float ss = 0.f;
                for (int e = lane; e < c1; e += 64) { float t = __expf(sl[e] - m); sl[e] = t; ss += t; }
                for (int o = 32; o > 0; o >>= 1) ss += __shfl_xor(ss, o);
                float r = 1.f / ss;
                for (int e = lane; e < c1; e += 64) sl[e] *= r;
            }
        }
        __syncthreads();
        if (tid < 128) {
            bool hi = tid >= 64;
            float acc = b2vv;
            for (int e = 0; e < c1; e++) {
                float a = hi ? sl1[e] : sl0[e];
                acc += a * sXl2[sslot[e] * 129 + tid];
            }
            semb[tid] = acc;
        }
        __syncthreads();
        // FC split-k (Wfc is L2-warm from the pre-spin prefetch)
        {
            int outc = tid & 127, k0 = (tid >> 7) << 6;
            float acc = 0.f;
            #pragma unroll 16
            for (int k = 0; k < 64; k++) acc += semb[k0 + k] * tld<F32>(Wfc, (k0 + k) * 128 + outc);
            sPartF[tid] = acc;
        }
        __syncthreads();
        if (tid < 128) {
            float o = bfcv + sPartF[tid] + sPartF[tid + 128];
            if (F32) ((float*)out)[tid] = o;
            else     ((__hip_bfloat16*)out)[tid] = __float2bfloat16(o);
        }
    }
}

__global__ void __launch_bounds__(THR)
k_tail(const void* x, const int* tgt,
       const void* Wl1, const void* bl1, const void* Wr1, const void* br1,
       const void* We1, const void* att1, const void* b1,
       const void* Wl2, const void* bl2, const void* Wr2, const void* br2,
       const void* We2, const void* att2, const void* b2v,
       const void* Wfc, const void* bfc,
       void* out, int* W)
{
    int t = tgt[0];
    if (W[3]) tail_body<true >(x, t, Wl1, bl1, Wr1, br1, We1, att1, b1,
                               Wl2, bl2, Wr2, br2, We2, att2, b2v, Wfc, bfc, out, W);
    else      tail_body<false>(x, t, Wl1, bl1, Wr1, br1, We1, att1, b1,
                               Wl2, bl2, Wr2, br2, We2, att2, b2v, Wfc, bfc, out, W);
}

// ---------------------------------------------------------------------------
extern "C" void kernel_launch(void* const* d_in, const int* in_sizes, int n_in,
                              void* d_out, int out_size, void* d_ws, size_t ws_size,
                              hipStream_t stream) {
    const void* x    = d_in[0];
    const int*  eidx = (const int*)d_in[1];
    const void* eattr= d_in[2];
    const int*  tgt  = (const int*)d_in[3];
    const void* Wl1 = d_in[4],  *bl1 = d_in[5],  *Wr1 = d_in[6],  *br1 = d_in[7];
    const void* We1 = d_in[8],  *att1= d_in[9],  *b1  = d_in[10];
    const void* Wl2 = d_in[11], *bl2 = d_in[12], *Wr2 = d_in[13], *br2 = d_in[14];
    const void* We2 = d_in[15], *att2= d_in[16], *b2v = d_in[17];
    const void* Wfc = d_in[18], *bfc = d_in[19];

    int E = in_sizes[1] / 2;
    const int* src = eidx;
    const int* dst = eidx + E;
    int* W = (int*)d_ws;

    k_scan1<<<NB1, THR, 0, stream>>>(x, src, dst, eattr, tgt, E, W);
    k_scan2<<<NB2, THR, 0, stream>>>(src, dst, eattr, tgt, E, W);
    k_tail <<<NTAIL, THR, 0, stream>>>(x, tgt, Wl1, bl1, Wr1, br1, We1, att1, b1,
                                       Wl2, bl2, Wr2, br2, We2, att2, b2v,
                                       Wfc, bfc, d_out, W);
}